// Round 1
// baseline (1783.777 us; speedup 1.0000x reference)
//
#include <hip/hip_runtime.h>

// Problem constants
#define NST 2048   // stocks
#define TLOOK 32
#define CDIM 512
#define TCAT 56

__device__ __forceinline__ float hswish(float x) {
  return x * fminf(fmaxf(x + 3.f, 0.f), 6.f) * (1.f / 6.f);
}

// ---------------------------------------------------------------------------
// Weight transpose: w[co, ci, k] -> B[(k*512+ci), co]   (GEMM-ready layout)
// ---------------------------------------------------------------------------
__global__ void transpose_w(const float* __restrict__ src, float* __restrict__ dst, int K) {
  int id = blockIdx.x * 256 + threadIdx.x;       // over K*512*512, writes coalesced
  int co = id & 511;
  int kk = id >> 9;          // k*512 + ci
  int ci = kk & 511;
  int k  = kk >> 9;
  dst[id] = src[(co * 512 + ci) * K + k];
}

// ---------------------------------------------------------------------------
// fp32 GEMM, C[M,512] = A@B + bias[col].  Tile 128x128x32, 256 thr, 8x8 micro.
// MODE 0: conv1 rows (n,ts): A-row = x + (n*32+2ts)*512, C-row = n*24+ts
// MODE 1: conv2 rows (n,ts): A-row = x + (n*32+4ts)*512, C-row = n*24+16+ts
// MODE 2: plain: A-row = r*K, C-row = r
// ---------------------------------------------------------------------------
template <int MODE>
__global__ __launch_bounds__(256) void gemm512(
    const float* __restrict__ A, const float* __restrict__ B,
    float* __restrict__ C, const float* __restrict__ bias, int M, int K) {
  __shared__ float As[32][132];   // transposed A tile [k][m]
  __shared__ float Bs[32][132];   // B tile [k][n]
  const int tid = threadIdx.x;
  const int tx = tid & 15;        // col group (cols tx*4 and 64+tx*4)
  const int ty = tid >> 4;        // row group
  const int r0 = blockIdx.x * 128;
  const int c0 = blockIdx.y * 128;

  float acc[8][8];
#pragma unroll
  for (int i = 0; i < 8; i++)
#pragma unroll
    for (int j = 0; j < 8; j++) acc[i][j] = 0.f;

  for (int kt = 0; kt < K; kt += 32) {
    __syncthreads();
#pragma unroll
    for (int l = 0; l < 4; l++) {
      int slot = tid + l * 256;              // 1024 float4 slots: A and B tiles
      int arow = slot >> 3, kq = slot & 7;   // A: row-major [128][32]
      int gr = r0 + arow;
      int aoff;
      if (MODE == 0)      aoff = ((gr >> 4) * 32 + ((gr & 15) << 1)) << 9;
      else if (MODE == 1) aoff = ((gr >> 3) * 32 + ((gr & 7) << 2)) << 9;
      else                aoff = gr * K;
      const float4 av = *(const float4*)(A + aoff + kt + kq * 4);
      As[kq * 4 + 0][arow] = av.x;
      As[kq * 4 + 1][arow] = av.y;
      As[kq * 4 + 2][arow] = av.z;
      As[kq * 4 + 3][arow] = av.w;
      int brow = slot >> 5, bc = slot & 31;  // B: [32][128]
      *(float4*)&Bs[brow][bc * 4] =
          *(const float4*)(B + (kt + brow) * 512 + c0 + bc * 4);
    }
    __syncthreads();
#pragma unroll
    for (int k = 0; k < 32; k++) {
      float4 a0 = *(const float4*)&As[k][ty * 4];
      float4 a1 = *(const float4*)&As[k][64 + ty * 4];
      float4 b0 = *(const float4*)&Bs[k][tx * 4];
      float4 b1 = *(const float4*)&Bs[k][64 + tx * 4];
      float ar[8] = {a0.x, a0.y, a0.z, a0.w, a1.x, a1.y, a1.z, a1.w};
      float br[8] = {b0.x, b0.y, b0.z, b0.w, b1.x, b1.y, b1.z, b1.w};
#pragma unroll
      for (int i = 0; i < 8; i++)
#pragma unroll
        for (int j = 0; j < 8; j++) acc[i][j] = fmaf(ar[i], br[j], acc[i][j]);
    }
  }

  float bb[8];
#pragma unroll
  for (int j = 0; j < 4; j++) {
    bb[j]     = bias[c0 + tx * 4 + j];
    bb[4 + j] = bias[c0 + 64 + tx * 4 + j];
  }

#pragma unroll
  for (int i = 0; i < 8; i++) {
    int gr = r0 + (i < 4 ? ty * 4 + i : 64 + ty * 4 + (i - 4));
    int crow;
    if (MODE == 0)      crow = (gr >> 4) * 24 + (gr & 15);
    else if (MODE == 1) crow = (gr >> 3) * 24 + 16 + (gr & 7);
    else                crow = gr;
    float4 o0, o1;
    o0.x = acc[i][0] + bb[0]; o0.y = acc[i][1] + bb[1];
    o0.z = acc[i][2] + bb[2]; o0.w = acc[i][3] + bb[3];
    o1.x = acc[i][4] + bb[4]; o1.y = acc[i][5] + bb[5];
    o1.z = acc[i][6] + bb[6]; o1.w = acc[i][7] + bb[7];
    *(float4*)(C + (long)crow * 512 + c0 + tx * 4) = o0;
    *(float4*)(C + (long)crow * 512 + c0 + 64 + tx * 4) = o1;
  }
}

// ---------------------------------------------------------------------------
// LayerNorm over [TS, 512] jointly, per stock, in place on fbuf.
// fbuf rows 0..15 = f1 (g1/b1), rows 16..23 = f2 (g2/b2)
// ---------------------------------------------------------------------------
__global__ __launch_bounds__(256) void ln_kernel(
    float* __restrict__ fbuf,
    const float* __restrict__ g1, const float* __restrict__ b1,
    const float* __restrict__ g2, const float* __restrict__ b2) {
  const int n = blockIdx.x;
  const int tid = threadIdx.x;
  const int w = tid >> 6, lane = tid & 63;
  __shared__ float ws1[4], ws2[4];
  float* base = fbuf + (long)n * 24 * 512;

  // ---- f1: 8192 floats ----
  {
    float4 v[8];
    float s = 0.f, sq = 0.f;
#pragma unroll
    for (int i = 0; i < 8; i++) {
      v[i] = *(const float4*)(base + (tid + i * 256) * 4);
      s += v[i].x + v[i].y + v[i].z + v[i].w;
      sq += v[i].x * v[i].x + v[i].y * v[i].y + v[i].z * v[i].z + v[i].w * v[i].w;
    }
    for (int d = 32; d; d >>= 1) { s += __shfl_down(s, d); sq += __shfl_down(sq, d); }
    if (lane == 0) { ws1[w] = s; ws2[w] = sq; }
    __syncthreads();
    float fs = ws1[0] + ws1[1] + ws1[2] + ws1[3];
    float fq = ws2[0] + ws2[1] + ws2[2] + ws2[3];
    float m = fs / 8192.f;
    float var = fq / 8192.f - m * m;
    float rstd = rsqrtf(var + 1e-5f);
#pragma unroll
    for (int i = 0; i < 8; i++) {
      int idx = (tid + i * 256) * 4;
      float4 gv = *(const float4*)(g1 + idx);
      float4 bv = *(const float4*)(b1 + idx);
      float4 o;
      o.x = (v[i].x - m) * rstd * gv.x + bv.x;
      o.y = (v[i].y - m) * rstd * gv.y + bv.y;
      o.z = (v[i].z - m) * rstd * gv.z + bv.z;
      o.w = (v[i].w - m) * rstd * gv.w + bv.w;
      *(float4*)(base + idx) = o;
    }
    __syncthreads();
  }
  // ---- f2: 4096 floats ----
  {
    float* base2 = base + 16 * 512;
    float4 v[4];
    float s = 0.f, sq = 0.f;
#pragma unroll
    for (int i = 0; i < 4; i++) {
      v[i] = *(const float4*)(base2 + (tid + i * 256) * 4);
      s += v[i].x + v[i].y + v[i].z + v[i].w;
      sq += v[i].x * v[i].x + v[i].y * v[i].y + v[i].z * v[i].z + v[i].w * v[i].w;
    }
    for (int d = 32; d; d >>= 1) { s += __shfl_down(s, d); sq += __shfl_down(sq, d); }
    if (lane == 0) { ws1[w] = s; ws2[w] = sq; }
    __syncthreads();
    float fs = ws1[0] + ws1[1] + ws1[2] + ws1[3];
    float fq = ws2[0] + ws2[1] + ws2[2] + ws2[3];
    float m = fs / 4096.f;
    float var = fq / 4096.f - m * m;
    float rstd = rsqrtf(var + 1e-5f);
#pragma unroll
    for (int i = 0; i < 4; i++) {
      int idx = (tid + i * 256) * 4;
      float4 gv = *(const float4*)(g2 + idx);
      float4 bv = *(const float4*)(b2 + idx);
      float4 o;
      o.x = (v[i].x - m) * rstd * gv.x + bv.x;
      o.y = (v[i].y - m) * rstd * gv.y + bv.y;
      o.z = (v[i].z - m) * rstd * gv.z + bv.z;
      o.w = (v[i].w - m) * rstd * gv.w + bv.w;
      *(float4*)(base2 + idx) = o;
    }
  }
}

// ---------------------------------------------------------------------------
// Fused TriU(2x) + hardswish + time-mean pooling. One block per (stock, half).
// Z[t][c] staged in LDS; h1 -> Hs (LDS); h2 -> pooled partial. mixed never
// materialized (only its mean is consumed downstream).
// ---------------------------------------------------------------------------
__global__ __launch_bounds__(256) void triu_pool(
    const float* __restrict__ x, const float* __restrict__ fbuf,
    const float* __restrict__ W1, const float* __restrict__ b1,
    const float* __restrict__ W2, const float* __restrict__ b2,
    float* __restrict__ pooled) {
  __shared__ float Z[56][256];
  __shared__ float Hs[56][256];
  __shared__ float W1t[56][64];   // W1t[t][s] = tril(W1)[s][t], s padded to 64
  __shared__ float W2t[56][64];
  __shared__ float pp[4][256];

  const int tid = threadIdx.x;
  const int n = blockIdx.x >> 1;
  const int half = blockIdx.x & 1;
  const int cb = half * 256;

  for (int idx = tid; idx < 56 * 64; idx += 256) {
    int t = idx >> 6, s = idx & 63;
    float w1v = (s < 56 && t <= s) ? W1[s * 56 + t] : 0.f;
    float w2v = (s < 56 && t <= s) ? W2[s * 56 + t] : 0.f;
    W1t[t][s] = w1v;
    W2t[t][s] = w2v;
  }
  for (int slot = tid; slot < 56 * 64; slot += 256) {
    int t = slot >> 6, cq = slot & 63;
    const float* src = (t < 32)
        ? (x + ((long)(n * 32 + t) * 512 + cb + cq * 4))
        : (fbuf + ((long)(n * 24 + (t - 32)) * 512 + cb + cq * 4));
    *(float4*)&Z[t][cq * 4] = *(const float4*)src;
  }
  __syncthreads();

  const int cg = tid >> 2, sg = tid & 3;   // cg in [0,64), sg in [0,4)
  const int c0 = cg * 4, s0 = sg * 16;

  float4 acc[16];
#pragma unroll
  for (int j = 0; j < 16; j++) acc[j] = make_float4(0.f, 0.f, 0.f, 0.f);

  // stage 1: h1[c, s] = sum_t Z[t][c] * W1t[t][s]
  for (int t = 0; t < 56; t++) {
    float4 a = *(const float4*)&Z[t][c0];
#pragma unroll
    for (int j4 = 0; j4 < 4; j4++) {
      float4 wv = *(const float4*)&W1t[t][s0 + j4 * 4];
      float wr[4] = {wv.x, wv.y, wv.z, wv.w};
#pragma unroll
      for (int jj = 0; jj < 4; jj++) {
        int j = j4 * 4 + jj;
        acc[j].x = fmaf(a.x, wr[jj], acc[j].x);
        acc[j].y = fmaf(a.y, wr[jj], acc[j].y);
        acc[j].z = fmaf(a.z, wr[jj], acc[j].z);
        acc[j].w = fmaf(a.w, wr[jj], acc[j].w);
      }
    }
  }
#pragma unroll
  for (int j = 0; j < 16; j++) {
    int s = s0 + j;
    if (s < 56) {
      float bs = b1[s];
      float4 h;
      h.x = hswish(acc[j].x + bs);
      h.y = hswish(acc[j].y + bs);
      h.z = hswish(acc[j].z + bs);
      h.w = hswish(acc[j].w + bs);
      *(float4*)&Hs[s][c0] = h;
    }
  }
  __syncthreads();

  // stage 2: h2[c, s] = sum_t Hs[t][c] * W2t[t][s]; pool over s
#pragma unroll
  for (int j = 0; j < 16; j++) acc[j] = make_float4(0.f, 0.f, 0.f, 0.f);
  for (int t = 0; t < 56; t++) {
    float4 a = *(const float4*)&Hs[t][c0];
#pragma unroll
    for (int j4 = 0; j4 < 4; j4++) {
      float4 wv = *(const float4*)&W2t[t][s0 + j4 * 4];
      float wr[4] = {wv.x, wv.y, wv.z, wv.w};
#pragma unroll
      for (int jj = 0; jj < 4; jj++) {
        int j = j4 * 4 + jj;
        acc[j].x = fmaf(a.x, wr[jj], acc[j].x);
        acc[j].y = fmaf(a.y, wr[jj], acc[j].y);
        acc[j].z = fmaf(a.z, wr[jj], acc[j].z);
        acc[j].w = fmaf(a.w, wr[jj], acc[j].w);
      }
    }
  }
  float4 ps = make_float4(0.f, 0.f, 0.f, 0.f);
#pragma unroll
  for (int j = 0; j < 16; j++) {
    int s = s0 + j;
    if (s < 56) {
      float bs = b2[s];
      ps.x += acc[j].x + bs;
      ps.y += acc[j].y + bs;
      ps.z += acc[j].z + bs;
      ps.w += acc[j].w + bs;
    }
  }
  *(float4*)&pp[sg][c0] = ps;
  __syncthreads();
  int c = tid;
  float tot = pp[0][c] + pp[1][c] + pp[2][c] + pp[3][c];
  pooled[(long)n * 512 + cb + c] = tot * (1.f / 56.f);
}

// ---------------------------------------------------------------------------
// Industry binning
// ---------------------------------------------------------------------------
__global__ void binzero(int* counts, int* cursor) {
  int i = threadIdx.x;
  if (i < 64) { counts[i] = 0; cursor[i] = 0; }
}
__global__ void bincount(const int* __restrict__ ids, int* counts) {
  int n = blockIdx.x * 256 + threadIdx.x;
  if (n < NST) atomicAdd(&counts[ids[n]], 1);
}
__global__ void binscan(const int* __restrict__ counts, int* offs) {
  int lane = threadIdx.x;  // 64 threads = 1 wave
  int incl = counts[lane];
  for (int d = 1; d < 64; d <<= 1) {
    int u = __shfl_up(incl, d);
    if (lane >= d) incl += u;
  }
  offs[lane + 1] = incl;
  if (lane == 0) offs[0] = 0;
}
__global__ void binscatter(const int* __restrict__ ids, const int* __restrict__ offs,
                           int* cursor, int* perm) {
  int n = blockIdx.x * 256 + threadIdx.x;
  if (n < NST) {
    int g = ids[n];
    int pos = offs[g] + atomicAdd(&cursor[g], 1);
    perm[pos] = n;
  }
}

// ---------------------------------------------------------------------------
// Block-sparse attention: block = (industry, head); wave per query row,
// flash-style over member chunks of 64. Writes attnv (pre-wo projection).
// ---------------------------------------------------------------------------
__global__ __launch_bounds__(256) void attn_kernel(
    const float* __restrict__ q, const float* __restrict__ k,
    const float* __restrict__ v, const int* __restrict__ offs,
    const int* __restrict__ perm, float* __restrict__ attnv) {
  const int g = blockIdx.x, h = blockIdx.y;
  const int off = offs[g];
  const int S = offs[g + 1] - off;
  const int w = threadIdx.x >> 6, lane = threadIdx.x & 63;
  __shared__ float pbuf[4][64];
  __shared__ int jbuf[4][64];

  for (int i = w; i < S; i += 4) {
    const int mi = perm[off + i];
    const float* qp = q + (long)mi * 512 + h * 64;
    float m_run = -1e30f, l_run = 0.f, o_d = 0.f;
    for (int jb = 0; jb < S; jb += 64) {
      int jc = min(64, S - jb);
      int mj = (lane < jc) ? perm[off + jb + lane] : 0;
      float sc = -1e30f;
      if (lane < jc) {
        const float* kp = k + (long)mj * 512 + h * 64;
        float a = 0.f;
#pragma unroll
        for (int d4 = 0; d4 < 16; d4++) {
          float4 qv = *(const float4*)(qp + d4 * 4);
          float4 kv = *(const float4*)(kp + d4 * 4);
          a += qv.x * kv.x + qv.y * kv.y + qv.z * kv.z + qv.w * kv.w;
        }
        sc = a * 0.125f;
      }
      float cm = sc;
      for (int d = 32; d; d >>= 1) cm = fmaxf(cm, __shfl_xor(cm, d));
      float m_new = fmaxf(m_run, cm);
      float resc = __expf(m_run - m_new);  // m_run=-1e30 -> 0, no NaN
      float p = (lane < jc) ? __expf(sc - m_new) : 0.f;
      float cs = p;
      for (int d = 32; d; d >>= 1) cs += __shfl_xor(cs, d);
      l_run = l_run * resc + cs;
      pbuf[w][lane] = p;
      jbuf[w][lane] = mj;
      float onew = o_d * resc;
      for (int j = 0; j < jc; j++) {
        float pj = pbuf[w][j];
        int mjj = jbuf[w][j];
        onew = fmaf(pj, v[(long)mjj * 512 + h * 64 + lane], onew);
      }
      o_d = onew;
      m_run = m_new;
    }
    attnv[(long)mi * 512 + h * 64 + lane] = o_d / l_run;
  }
}

// ---------------------------------------------------------------------------
// wowp[i] = sum_j wo[i,j]*wp[j];  const = dot(bo, wp) + bp
// ---------------------------------------------------------------------------
__global__ void wowp_kernel(const float* __restrict__ wo, const float* __restrict__ wp,
                            const float* __restrict__ bo, const float* __restrict__ bp,
                            float* wowp, float* constbuf) {
  int w = threadIdx.x >> 6, lane = threadIdx.x & 63;
  int gw = blockIdx.x * 4 + w;  // 32 waves
  for (int row = gw; row < 512; row += 32) {
    float partial = 0.f;
    for (int e = lane; e < 512; e += 64) partial += wo[(long)row * 512 + e] * wp[e];
    for (int d = 32; d; d >>= 1) partial += __shfl_xor(partial, d);
    if (lane == 0) wowp[row] = partial;
  }
  if (blockIdx.x == 0 && w == 0) {
    float partial = 0.f;
    for (int e = lane; e < 512; e += 64) partial += bo[e] * wp[e];
    for (int d = 32; d; d >>= 1) partial += __shfl_xor(partial, d);
    if (lane == 0) constbuf[0] = partial + bp[0];
  }
}

// out[n] = dot(pooled[n], wp) + dot(attnv[n], wowp) + const
__global__ void final_kernel(const float* __restrict__ pooled,
                             const float* __restrict__ attnv,
                             const float* __restrict__ wp,
                             const float* __restrict__ wowp,
                             const float* __restrict__ constbuf,
                             float* __restrict__ out) {
  int w = threadIdx.x >> 6, lane = threadIdx.x & 63;
  int row = blockIdx.x * 4 + w;  // grid 512 -> 2048 rows
  float partial = 0.f;
#pragma unroll
  for (int e8 = 0; e8 < 8; e8++) {
    int e = lane + e8 * 64;
    partial += pooled[(long)row * 512 + e] * wp[e] + attnv[(long)row * 512 + e] * wowp[e];
  }
  for (int d = 32; d; d >>= 1) partial += __shfl_xor(partial, d);
  if (lane == 0) out[row] = partial + constbuf[0];
}

// ---------------------------------------------------------------------------
extern "C" void kernel_launch(void* const* d_in, const int* in_sizes, int n_in,
                              void* d_out, int out_size, void* d_ws, size_t ws_size,
                              hipStream_t stream) {
  const float* x   = (const float*)d_in[0];
  const int*   ids = (const int*)d_in[1];
  const float* w1  = (const float*)d_in[2];
  const float* cb1 = (const float*)d_in[3];
  const float* w2  = (const float*)d_in[4];
  const float* cb2 = (const float*)d_in[5];
  const float* g1  = (const float*)d_in[6];
  const float* lb1 = (const float*)d_in[7];
  const float* g2  = (const float*)d_in[8];
  const float* lb2 = (const float*)d_in[9];
  const float* tw1 = (const float*)d_in[10];
  const float* tb1 = (const float*)d_in[11];
  const float* tw2 = (const float*)d_in[12];
  const float* tb2 = (const float*)d_in[13];
  const float* wq  = (const float*)d_in[14];
  const float* bq  = (const float*)d_in[15];
  const float* wk  = (const float*)d_in[16];
  const float* bk  = (const float*)d_in[17];
  const float* wv  = (const float*)d_in[18];
  const float* bv  = (const float*)d_in[19];
  const float* wo  = (const float*)d_in[20];
  const float* bo  = (const float*)d_in[21];
  const float* wp  = (const float*)d_in[22];
  const float* bp  = (const float*)d_in[23];
  float* out = (float*)d_out;

  // Workspace carve-out (~127 MB total)
  char* ws = (char*)d_ws;
  size_t off = 0;
  auto alloc = [&](size_t bytes) {
    void* p = ws + off;
    off += (bytes + 255) & ~(size_t)255;
    return p;
  };
  float* B1     = (float*)alloc((size_t)1024 * 512 * 4);
  float* B2     = (float*)alloc((size_t)2048 * 512 * 4);
  float* fbuf   = (float*)alloc((size_t)NST * 24 * 512 * 4);
  float* pooled = (float*)alloc((size_t)NST * 512 * 4);
  float* qb     = (float*)alloc((size_t)NST * 512 * 4);
  float* kb     = (float*)alloc((size_t)NST * 512 * 4);
  float* vb     = (float*)alloc((size_t)NST * 512 * 4);
  float* attnv  = (float*)alloc((size_t)NST * 512 * 4);
  float* wowp   = (float*)alloc(512 * 4);
  float* cbuf   = (float*)alloc(4);
  int* counts   = (int*)alloc(64 * 4);
  int* cursor   = (int*)alloc(64 * 4);
  int* offs     = (int*)alloc(65 * 4);
  int* perm     = (int*)alloc(NST * 4);

  transpose_w<<<dim3(1024 * 512 / 256), 256, 0, stream>>>(w1, B1, 2);
  transpose_w<<<dim3(2048 * 512 / 256), 256, 0, stream>>>(w2, B2, 4);

  // conv1: M=32768, K=1024; conv2: M=16384, K=2048 (GEMMs on views of x)
  gemm512<0><<<dim3(256, 4), 256, 0, stream>>>(x, B1, fbuf, cb1, 32768, 1024);
  gemm512<1><<<dim3(128, 4), 256, 0, stream>>>(x, B2, fbuf, cb2, 16384, 2048);
  ln_kernel<<<NST, 256, 0, stream>>>(fbuf, g1, lb1, g2, lb2);
  triu_pool<<<NST * 2, 256, 0, stream>>>(x, fbuf, tw1, tb1, tw2, tb2, pooled);

  gemm512<2><<<dim3(16, 4), 256, 0, stream>>>(pooled, wq, qb, bq, NST, 512);
  gemm512<2><<<dim3(16, 4), 256, 0, stream>>>(pooled, wk, kb, bk, NST, 512);
  gemm512<2><<<dim3(16, 4), 256, 0, stream>>>(pooled, wv, vb, bv, NST, 512);

  binzero<<<1, 64, 0, stream>>>(counts, cursor);
  bincount<<<8, 256, 0, stream>>>(ids, counts);
  binscan<<<1, 64, 0, stream>>>(counts, offs);
  binscatter<<<8, 256, 0, stream>>>(ids, offs, cursor, perm);
  wowp_kernel<<<8, 256, 0, stream>>>(wo, wp, bo, bp, wowp, cbuf);

  attn_kernel<<<dim3(64, 8), 256, 0, stream>>>(qb, kb, vb, offs, perm, attnv);
  final_kernel<<<512, 256, 0, stream>>>(pooled, attnv, wp, wowp, cbuf, out);
}

// Round 2
// 985.362 us; speedup vs baseline: 1.8103x; 1.8103x over previous
//
#include <hip/hip_runtime.h>

#define NST 2048   // stocks

typedef __attribute__((ext_vector_type(8))) short bf16x8;
typedef __attribute__((ext_vector_type(4))) float f32x4;
typedef __attribute__((ext_vector_type(8))) unsigned short u16x8;

__device__ __forceinline__ float hswish(float x) {
  return x * fminf(fmaxf(x + 3.f, 0.f), 6.f) * (1.f / 6.f);
}

__device__ __forceinline__ unsigned short f2bf(float f) {
  unsigned int u = __float_as_uint(f);
  u += 0x7fffu + ((u >> 16) & 1u);
  return (unsigned short)(u >> 16);
}

__device__ __forceinline__ void gload16(const void* g, void* l) {
  __builtin_amdgcn_global_load_lds(
      (const __attribute__((address_space(1))) void*)g,
      (__attribute__((address_space(3))) void*)l, 16, 0, 0);
}

// ---------------------------------------------------------------------------
// x [2048,32,512] fp32 -> bf16 (8 elems/thread)
// ---------------------------------------------------------------------------
__global__ __launch_bounds__(256) void x_to_bf16(const float* __restrict__ x,
                                                 unsigned short* __restrict__ xb) {
  long id = (long)(blockIdx.x * 256 + threadIdx.x) * 8;
  float4 a = *(const float4*)(x + id);
  float4 b = *(const float4*)(x + id + 4);
  u16x8 o;
  o[0] = f2bf(a.x); o[1] = f2bf(a.y); o[2] = f2bf(a.z); o[3] = f2bf(a.w);
  o[4] = f2bf(b.x); o[5] = f2bf(b.y); o[6] = f2bf(b.z); o[7] = f2bf(b.w);
  *(u16x8*)(xb + id) = o;
}

// ---------------------------------------------------------------------------
// conv weight w[co,ci,k] -> Bt[co][k*512+ci] bf16 (B^T layout, row=out unit)
// ---------------------------------------------------------------------------
__global__ __launch_bounds__(256) void conv_w_to_bt(const float* __restrict__ src,
                                                    unsigned short* __restrict__ dst,
                                                    int Kw, int rlshift) {
  int id = blockIdx.x * 256 + threadIdx.x;
  int co = id >> rlshift;
  int idx = id & ((1 << rlshift) - 1);
  int ci = idx & 511;
  int k = idx >> 9;
  dst[id] = f2bf(src[((co << 9) + ci) * Kw + k]);
}

// wq/wk/wv [in][out] -> Bqkv[o][in] bf16 (o in [0,1536)), bias concat
__global__ __launch_bounds__(256) void qkv_w_to_bt(
    const float* __restrict__ wq, const float* __restrict__ wk,
    const float* __restrict__ wv, const float* __restrict__ bq,
    const float* __restrict__ bk, const float* __restrict__ bv,
    unsigned short* __restrict__ Bt, float* __restrict__ bias) {
  int id = blockIdx.x * 256 + threadIdx.x;   // over 1536*512
  int o = id >> 9, i = id & 511;
  int oc = o & 511;
  const float* w = (o < 512) ? wq : (o < 1024) ? wk : wv;
  Bt[id] = f2bf(w[(i << 9) + oc]);
  if (i == 0) bias[o] = (o < 512) ? bq[oc] : (o < 1024) ? bk[oc] : bv[oc];
}

// ---------------------------------------------------------------------------
// bf16 MFMA GEMM: C[M,N] = A(view) @ Bt^T + bias.  Bt is [N][K] bf16.
// Tile 128x128xBK64, 256 thr = 4 waves (2x2), wave tile 64x64 = 4x4 frags
// of 16x16, mfma_f32_16x16x32_bf16, fp32 accum.  global_load_lds width-16
// staging; LDS XOR-swizzled (slot ^= row&7) on the global-source side,
// un-swizzled on the ds_read_b128 side -> 2-way bank aliasing (free).
// MODE 0: conv1 A-row gr -> x+((gr>>4)*32+((gr&15)<<1))*512, crow=(gr>>4)*24+(gr&15)
// MODE 1: conv2 A-row gr -> x+((gr>>3)*32+((gr&7)<<2))*512, crow=(gr>>3)*24+16+(gr&7)
// MODE 2: plain A-row gr*K, crow=gr
// ---------------------------------------------------------------------------
template <int MODE>
__global__ __launch_bounds__(256) void gemm_bt(
    const unsigned short* __restrict__ A, const unsigned short* __restrict__ Bt,
    float* __restrict__ C, const float* __restrict__ bias, int K, int ldc) {
  __shared__ unsigned short As[128 * 64];
  __shared__ unsigned short Bs[128 * 64];
  const int tid = threadIdx.x;
  const int wid = tid >> 6;
  const int lane = tid & 63;
  const int r0 = blockIdx.x * 128;
  const int c0 = blockIdx.y * 128;
  const int wr = (wid >> 1) * 64;
  const int wc = (wid & 1) * 64;
  const int srow = lane >> 3;   // 0..7 (row within an 8-row staging instr)
  const int sslot = lane & 7;   // 0..7 (16B slot within 128B row)

  long aoffl[4], boffl[4];
  unsigned short* adst[4];
  unsigned short* bdst[4];
#pragma unroll
  for (int l = 0; l < 4; l++) {
    const int r = (wid * 4 + l) * 8 + srow;   // tile row 0..127
    const int gr = r0 + r;
    long ao;
    if (MODE == 0)      ao = (long)(((gr >> 4) * 32) + ((gr & 15) << 1)) << 9;
    else if (MODE == 1) ao = (long)(((gr >> 3) * 32) + ((gr & 7) << 2)) << 9;
    else                ao = (long)gr * K;
    const int sw = (sslot ^ (r & 7)) << 3;    // swizzled k-offset (elements)
    aoffl[l] = ao + sw;
    boffl[l] = (long)(c0 + r) * K + sw;
    adst[l] = &As[(wid * 4 + l) * 8 * 64];
    bdst[l] = &Bs[(wid * 4 + l) * 8 * 64];
  }

  f32x4 acc[4][4];
#pragma unroll
  for (int m = 0; m < 4; m++)
#pragma unroll
    for (int n = 0; n < 4; n++) acc[m][n] = (f32x4){0.f, 0.f, 0.f, 0.f};

  const int fr = lane & 15;   // row (A) / col (B) within fragment
  const int fq = lane >> 4;   // k-quarter

  for (int kt = 0; kt < K; kt += 64) {
#pragma unroll
    for (int l = 0; l < 4; l++) {
      gload16(A + aoffl[l] + kt, adst[l]);
      gload16(Bt + boffl[l] + kt, bdst[l]);
    }
    __syncthreads();   // compiler drains vmcnt before barrier -> tile ready
#pragma unroll
    for (int ks = 0; ks < 2; ks++) {
      const int kq = ks * 4 + fq;   // 16B k-slot 0..7
      bf16x8 af[4], bfr[4];
#pragma unroll
      for (int m = 0; m < 4; m++) {
        const int rr = wr + m * 16 + fr;
        af[m] = *(const bf16x8*)&As[rr * 64 + ((kq ^ (rr & 7)) << 3)];
      }
#pragma unroll
      for (int n = 0; n < 4; n++) {
        const int cc = wc + n * 16 + fr;
        bfr[n] = *(const bf16x8*)&Bs[cc * 64 + ((kq ^ (cc & 7)) << 3)];
      }
#pragma unroll
      for (int m = 0; m < 4; m++)
#pragma unroll
        for (int n = 0; n < 4; n++)
          acc[m][n] = __builtin_amdgcn_mfma_f32_16x16x32_bf16(
              af[m], bfr[n], acc[m][n], 0, 0, 0);
    }
    __syncthreads();   // all waves done reading before next stage overwrites
  }

  float bv[4];
#pragma unroll
  for (int n = 0; n < 4; n++) bv[n] = bias[c0 + wc + n * 16 + fr];

#pragma unroll
  for (int m = 0; m < 4; m++) {
#pragma unroll
    for (int j = 0; j < 4; j++) {
      const int gr = r0 + wr + m * 16 + fq * 4 + j;
      int crow;
      if (MODE == 0)      crow = (gr >> 4) * 24 + (gr & 15);
      else if (MODE == 1) crow = (gr >> 3) * 24 + 16 + (gr & 7);
      else                crow = gr;
      float* cp = C + (long)crow * ldc + c0 + wc + fr;
#pragma unroll
      for (int n = 0; n < 4; n++) cp[n * 16] = acc[m][n][j] + bv[n];
    }
  }
}

// ---------------------------------------------------------------------------
// LayerNorm over [TS, 512] jointly, per stock, in place on fbuf (fp32).
// ---------------------------------------------------------------------------
__global__ __launch_bounds__(256) void ln_kernel(
    float* __restrict__ fbuf,
    const float* __restrict__ g1, const float* __restrict__ b1,
    const float* __restrict__ g2, const float* __restrict__ b2) {
  const int n = blockIdx.x;
  const int tid = threadIdx.x;
  const int w = tid >> 6, lane = tid & 63;
  __shared__ float ws1[4], ws2[4];
  float* base = fbuf + (long)n * 24 * 512;

  {
    float4 v[8];
    float s = 0.f, sq = 0.f;
#pragma unroll
    for (int i = 0; i < 8; i++) {
      v[i] = *(const float4*)(base + (tid + i * 256) * 4);
      s += v[i].x + v[i].y + v[i].z + v[i].w;
      sq += v[i].x * v[i].x + v[i].y * v[i].y + v[i].z * v[i].z + v[i].w * v[i].w;
    }
    for (int d = 32; d; d >>= 1) { s += __shfl_down(s, d); sq += __shfl_down(sq, d); }
    if (lane == 0) { ws1[w] = s; ws2[w] = sq; }
    __syncthreads();
    float fs = ws1[0] + ws1[1] + ws1[2] + ws1[3];
    float fq = ws2[0] + ws2[1] + ws2[2] + ws2[3];
    float m = fs / 8192.f;
    float var = fq / 8192.f - m * m;
    float rstd = rsqrtf(var + 1e-5f);
#pragma unroll
    for (int i = 0; i < 8; i++) {
      int idx = (tid + i * 256) * 4;
      float4 gv = *(const float4*)(g1 + idx);
      float4 bvv = *(const float4*)(b1 + idx);
      float4 o;
      o.x = (v[i].x - m) * rstd * gv.x + bvv.x;
      o.y = (v[i].y - m) * rstd * gv.y + bvv.y;
      o.z = (v[i].z - m) * rstd * gv.z + bvv.z;
      o.w = (v[i].w - m) * rstd * gv.w + bvv.w;
      *(float4*)(base + idx) = o;
    }
    __syncthreads();
  }
  {
    float* base2 = base + 16 * 512;
    float4 v[4];
    float s = 0.f, sq = 0.f;
#pragma unroll
    for (int i = 0; i < 4; i++) {
      v[i] = *(const float4*)(base2 + (tid + i * 256) * 4);
      s += v[i].x + v[i].y + v[i].z + v[i].w;
      sq += v[i].x * v[i].x + v[i].y * v[i].y + v[i].z * v[i].z + v[i].w * v[i].w;
    }
    for (int d = 32; d; d >>= 1) { s += __shfl_down(s, d); sq += __shfl_down(sq, d); }
    if (lane == 0) { ws1[w] = s; ws2[w] = sq; }
    __syncthreads();
    float fs = ws1[0] + ws1[1] + ws1[2] + ws1[3];
    float fq = ws2[0] + ws2[1] + ws2[2] + ws2[3];
    float m = fs / 4096.f;
    float var = fq / 4096.f - m * m;
    float rstd = rsqrtf(var + 1e-5f);
#pragma unroll
    for (int i = 0; i < 4; i++) {
      int idx = (tid + i * 256) * 4;
      float4 gv = *(const float4*)(g2 + idx);
      float4 bvv = *(const float4*)(b2 + idx);
      float4 o;
      o.x = (v[i].x - m) * rstd * gv.x + bvv.x;
      o.y = (v[i].y - m) * rstd * gv.y + bvv.y;
      o.z = (v[i].z - m) * rstd * gv.z + bvv.z;
      o.w = (v[i].w - m) * rstd * gv.w + bvv.w;
      *(float4*)(base2 + idx) = o;
    }
  }
}

// ---------------------------------------------------------------------------
// Fused TriU(2x) + hardswish + time-mean pooling; writes pooled fp32 + bf16.
// ---------------------------------------------------------------------------
__global__ __launch_bounds__(256) void triu_pool(
    const float* __restrict__ x, const float* __restrict__ fbuf,
    const float* __restrict__ W1, const float* __restrict__ b1,
    const float* __restrict__ W2, const float* __restrict__ b2,
    float* __restrict__ pooled, unsigned short* __restrict__ pooledbf) {
  __shared__ float Z[56][256];
  __shared__ float Hs[56][256];
  __shared__ float W1t[56][64];
  __shared__ float W2t[56][64];
  __shared__ float pp[4][256];

  const int tid = threadIdx.x;
  const int n = blockIdx.x >> 1;
  const int half = blockIdx.x & 1;
  const int cb = half * 256;

  for (int idx = tid; idx < 56 * 64; idx += 256) {
    int t = idx >> 6, s = idx & 63;
    float w1v = (s < 56 && t <= s) ? W1[s * 56 + t] : 0.f;
    float w2v = (s < 56 && t <= s) ? W2[s * 56 + t] : 0.f;
    W1t[t][s] = w1v;
    W2t[t][s] = w2v;
  }
  for (int slot = tid; slot < 56 * 64; slot += 256) {
    int t = slot >> 6, cq = slot & 63;
    const float* src = (t < 32)
        ? (x + ((long)(n * 32 + t) * 512 + cb + cq * 4))
        : (fbuf + ((long)(n * 24 + (t - 32)) * 512 + cb + cq * 4));
    *(float4*)&Z[t][cq * 4] = *(const float4*)src;
  }
  __syncthreads();

  const int cg = tid >> 2, sg = tid & 3;
  const int c0 = cg * 4, s0 = sg * 16;

  float4 acc[16];
#pragma unroll
  for (int j = 0; j < 16; j++) acc[j] = make_float4(0.f, 0.f, 0.f, 0.f);

  for (int t = 0; t < 56; t++) {
    float4 a = *(const float4*)&Z[t][c0];
#pragma unroll
    for (int j4 = 0; j4 < 4; j4++) {
      float4 wv = *(const float4*)&W1t[t][s0 + j4 * 4];
      float wr[4] = {wv.x, wv.y, wv.z, wv.w};
#pragma unroll
      for (int jj = 0; jj < 4; jj++) {
        int j = j4 * 4 + jj;
        acc[j].x = fmaf(a.x, wr[jj], acc[j].x);
        acc[j].y = fmaf(a.y, wr[jj], acc[j].y);
        acc[j].z = fmaf(a.z, wr[jj], acc[j].z);
        acc[j].w = fmaf(a.w, wr[jj], acc[j].w);
      }
    }
  }
#pragma unroll
  for (int j = 0; j < 16; j++) {
    int s = s0 + j;
    if (s < 56) {
      float bs = b1[s];
      float4 h;
      h.x = hswish(acc[j].x + bs);
      h.y = hswish(acc[j].y + bs);
      h.z = hswish(acc[j].z + bs);
      h.w = hswish(acc[j].w + bs);
      *(float4*)&Hs[s][c0] = h;
    }
  }
  __syncthreads();

#pragma unroll
  for (int j = 0; j < 16; j++) acc[j] = make_float4(0.f, 0.f, 0.f, 0.f);
  for (int t = 0; t < 56; t++) {
    float4 a = *(const float4*)&Hs[t][c0];
#pragma unroll
    for (int j4 = 0; j4 < 4; j4++) {
      float4 wv = *(const float4*)&W2t[t][s0 + j4 * 4];
      float wr[4] = {wv.x, wv.y, wv.z, wv.w};
#pragma unroll
      for (int jj = 0; jj < 4; jj++) {
        int j = j4 * 4 + jj;
        acc[j].x = fmaf(a.x, wr[jj], acc[j].x);
        acc[j].y = fmaf(a.y, wr[jj], acc[j].y);
        acc[j].z = fmaf(a.z, wr[jj], acc[j].z);
        acc[j].w = fmaf(a.w, wr[jj], acc[j].w);
      }
    }
  }
  float4 ps = make_float4(0.f, 0.f, 0.f, 0.f);
#pragma unroll
  for (int j = 0; j < 16; j++) {
    int s = s0 + j;
    if (s < 56) {
      float bs = b2[s];
      ps.x += acc[j].x + bs;
      ps.y += acc[j].y + bs;
      ps.z += acc[j].z + bs;
      ps.w += acc[j].w + bs;
    }
  }
  *(float4*)&pp[sg][c0] = ps;
  __syncthreads();
  int c = tid;
  float tot = pp[0][c] + pp[1][c] + pp[2][c] + pp[3][c];
  float pv = tot * (1.f / 56.f);
  pooled[(long)n * 512 + cb + c] = pv;
  pooledbf[(long)n * 512 + cb + c] = f2bf(pv);
}

// ---------------------------------------------------------------------------
// Industry binning
// ---------------------------------------------------------------------------
__global__ void binzero(int* counts, int* cursor) {
  int i = threadIdx.x;
  if (i < 64) { counts[i] = 0; cursor[i] = 0; }
}
__global__ void bincount(const int* __restrict__ ids, int* counts) {
  int n = blockIdx.x * 256 + threadIdx.x;
  if (n < NST) atomicAdd(&counts[ids[n]], 1);
}
__global__ void binscan(const int* __restrict__ counts, int* offs) {
  int lane = threadIdx.x;
  int incl = counts[lane];
  for (int d = 1; d < 64; d <<= 1) {
    int u = __shfl_up(incl, d);
    if (lane >= d) incl += u;
  }
  offs[lane + 1] = incl;
  if (lane == 0) offs[0] = 0;
}
__global__ void binscatter(const int* __restrict__ ids, const int* __restrict__ offs,
                           int* cursor, int* perm) {
  int n = blockIdx.x * 256 + threadIdx.x;
  if (n < NST) {
    int g = ids[n];
    int pos = offs[g] + atomicAdd(&cursor[g], 1);
    perm[pos] = n;
  }
}

// ---------------------------------------------------------------------------
// Block-sparse attention over fused qkv buffer [N][1536] (q|k|v)
// ---------------------------------------------------------------------------
__global__ __launch_bounds__(256) void attn_kernel(
    const float* __restrict__ qkv, const int* __restrict__ offs,
    const int* __restrict__ perm, float* __restrict__ attnv) {
  const int g = blockIdx.x, h = blockIdx.y;
  const int off = offs[g];
  const int S = offs[g + 1] - off;
  const int w = threadIdx.x >> 6, lane = threadIdx.x & 63;
  __shared__ float pbuf[4][64];
  __shared__ int jbuf[4][64];

  for (int i = w; i < S; i += 4) {
    const int mi = perm[off + i];
    const float* qp = qkv + (long)mi * 1536 + h * 64;
    float m_run = -1e30f, l_run = 0.f, o_d = 0.f;
    for (int jb = 0; jb < S; jb += 64) {
      int jc = min(64, S - jb);
      int mj = (lane < jc) ? perm[off + jb + lane] : 0;
      float sc = -1e30f;
      if (lane < jc) {
        const float* kp = qkv + (long)mj * 1536 + 512 + h * 64;
        float a = 0.f;
#pragma unroll
        for (int d4 = 0; d4 < 16; d4++) {
          float4 qv = *(const float4*)(qp + d4 * 4);
          float4 kv = *(const float4*)(kp + d4 * 4);
          a += qv.x * kv.x + qv.y * kv.y + qv.z * kv.z + qv.w * kv.w;
        }
        sc = a * 0.125f;
      }
      float cm = sc;
      for (int d = 32; d; d >>= 1) cm = fmaxf(cm, __shfl_xor(cm, d));
      float m_new = fmaxf(m_run, cm);
      float resc = __expf(m_run - m_new);
      float p = (lane < jc) ? __expf(sc - m_new) : 0.f;
      float cs = p;
      for (int d = 32; d; d >>= 1) cs += __shfl_xor(cs, d);
      l_run = l_run * resc + cs;
      pbuf[w][lane] = p;
      jbuf[w][lane] = mj;
      float onew = o_d * resc;
      for (int j = 0; j < jc; j++) {
        float pj = pbuf[w][j];
        int mjj = jbuf[w][j];
        onew = fmaf(pj, qkv[(long)mjj * 1536 + 1024 + h * 64 + lane], onew);
      }
      o_d = onew;
      m_run = m_new;
    }
    attnv[(long)mi * 512 + h * 64 + lane] = o_d / l_run;
  }
}

// ---------------------------------------------------------------------------
__global__ void wowp_kernel(const float* __restrict__ wo, const float* __restrict__ wp,
                            const float* __restrict__ bo, const float* __restrict__ bp,
                            float* wowp, float* constbuf) {
  int w = threadIdx.x >> 6, lane = threadIdx.x & 63;
  int gw = blockIdx.x * 4 + w;
  for (int row = gw; row < 512; row += 32) {
    float partial = 0.f;
    for (int e = lane; e < 512; e += 64) partial += wo[(long)row * 512 + e] * wp[e];
    for (int d = 32; d; d >>= 1) partial += __shfl_xor(partial, d);
    if (lane == 0) wowp[row] = partial;
  }
  if (blockIdx.x == 0 && w == 0) {
    float partial = 0.f;
    for (int e = lane; e < 512; e += 64) partial += bo[e] * wp[e];
    for (int d = 32; d; d >>= 1) partial += __shfl_xor(partial, d);
    if (lane == 0) constbuf[0] = partial + bp[0];
  }
}

__global__ void final_kernel(const float* __restrict__ pooled,
                             const float* __restrict__ attnv,
                             const float* __restrict__ wp,
                             const float* __restrict__ wowp,
                             const float* __restrict__ constbuf,
                             float* __restrict__ out) {
  int w = threadIdx.x >> 6, lane = threadIdx.x & 63;
  int row = blockIdx.x * 4 + w;
  float partial = 0.f;
#pragma unroll
  for (int e8 = 0; e8 < 8; e8++) {
    int e = lane + e8 * 64;
    partial += pooled[(long)row * 512 + e] * wp[e] + attnv[(long)row * 512 + e] * wowp[e];
  }
  for (int d = 32; d; d >>= 1) partial += __shfl_xor(partial, d);
  if (lane == 0) out[row] = partial + constbuf[0];
}

// ---------------------------------------------------------------------------
extern "C" void kernel_launch(void* const* d_in, const int* in_sizes, int n_in,
                              void* d_out, int out_size, void* d_ws, size_t ws_size,
                              hipStream_t stream) {
  const float* x   = (const float*)d_in[0];
  const int*   ids = (const int*)d_in[1];
  const float* w1  = (const float*)d_in[2];
  const float* cb1 = (const float*)d_in[3];
  const float* w2  = (const float*)d_in[4];
  const float* cb2 = (const float*)d_in[5];
  const float* g1  = (const float*)d_in[6];
  const float* lb1 = (const float*)d_in[7];
  const float* g2  = (const float*)d_in[8];
  const float* lb2 = (const float*)d_in[9];
  const float* tw1 = (const float*)d_in[10];
  const float* tb1 = (const float*)d_in[11];
  const float* tw2 = (const float*)d_in[12];
  const float* tb2 = (const float*)d_in[13];
  const float* wq  = (const float*)d_in[14];
  const float* bq  = (const float*)d_in[15];
  const float* wk  = (const float*)d_in[16];
  const float* bk  = (const float*)d_in[17];
  const float* wv  = (const float*)d_in[18];
  const float* bv  = (const float*)d_in[19];
  const float* wo  = (const float*)d_in[20];
  const float* bo  = (const float*)d_in[21];
  const float* wp  = (const float*)d_in[22];
  const float* bp  = (const float*)d_in[23];
  float* out = (float*)d_out;

  char* ws = (char*)d_ws;
  size_t off = 0;
  auto alloc = [&](size_t bytes) {
    void* p = ws + off;
    off += (bytes + 255) & ~(size_t)255;
    return p;
  };
  unsigned short* xbf  = (unsigned short*)alloc((size_t)NST * 32 * 512 * 2);  // 67 MB
  unsigned short* B1b  = (unsigned short*)alloc((size_t)512 * 1024 * 2);
  unsigned short* B2b  = (unsigned short*)alloc((size_t)512 * 2048 * 2);
  unsigned short* Bqkv = (unsigned short*)alloc((size_t)1536 * 512 * 2);
  float* bqkv   = (float*)alloc(1536 * 4);
  float* fbuf   = (float*)alloc((size_t)NST * 24 * 512 * 4);                  // 100 MB
  float* pooled = (float*)alloc((size_t)NST * 512 * 4);
  unsigned short* pooledbf = (unsigned short*)alloc((size_t)NST * 512 * 2);
  float* qkvb   = (float*)alloc((size_t)NST * 1536 * 4);
  float* attnv  = (float*)alloc((size_t)NST * 512 * 4);
  float* wowp   = (float*)alloc(512 * 4);
  float* cbuf   = (float*)alloc(4);
  int* counts   = (int*)alloc(64 * 4);
  int* cursor   = (int*)alloc(64 * 4);
  int* offs     = (int*)alloc(65 * 4);
  int* perm     = (int*)alloc(NST * 4);

  // prep: conversions + weight transposes
  x_to_bf16<<<dim3(NST * 32 * 512 / (256 * 8)), 256, 0, stream>>>(x, xbf);
  conv_w_to_bt<<<dim3(512 * 1024 / 256), 256, 0, stream>>>(w1, B1b, 2, 10);
  conv_w_to_bt<<<dim3(512 * 2048 / 256), 256, 0, stream>>>(w2, B2b, 4, 11);
  qkv_w_to_bt<<<dim3(1536 * 512 / 256), 256, 0, stream>>>(wq, wk, wv, bq, bk, bv, Bqkv, bqkv);
  binzero<<<1, 64, 0, stream>>>(counts, cursor);
  bincount<<<8, 256, 0, stream>>>(ids, counts);
  binscan<<<1, 64, 0, stream>>>(counts, offs);
  binscatter<<<8, 256, 0, stream>>>(ids, offs, cursor, perm);
  wowp_kernel<<<8, 256, 0, stream>>>(wo, wp, bo, bp, wowp, cbuf);

  // conv1: M=32768 K=1024; conv2: M=16384 K=2048 (bf16 MFMA GEMMs on views)
  gemm_bt<0><<<dim3(256, 4), 256, 0, stream>>>(xbf, B1b, fbuf, cb1, 1024, 512);
  gemm_bt<1><<<dim3(128, 4), 256, 0, stream>>>(xbf, B2b, fbuf, cb2, 2048, 512);
  ln_kernel<<<NST, 256, 0, stream>>>(fbuf, g1, lb1, g2, lb2);
  triu_pool<<<NST * 2, 256, 0, stream>>>(x, fbuf, tw1, tb1, tw2, tb2, pooled, pooledbf);

  // fused q|k|v: M=2048 N=1536 K=512
  gemm_bt<2><<<dim3(16, 12), 256, 0, stream>>>(pooledbf, Bqkv, qkvb, bqkv, 512, 1536);

  attn_kernel<<<dim3(64, 8), 256, 0, stream>>>(qkvb, offs, perm, attnv);
  final_kernel<<<512, 256, 0, stream>>>(pooled, attnv, wp, wowp, cbuf, out);
}

// Round 3
// 755.090 us; speedup vs baseline: 2.3623x; 1.3050x over previous
//
#include <hip/hip_runtime.h>

#define NST 2048   // stocks

typedef __attribute__((ext_vector_type(8))) short bf16x8;
typedef __attribute__((ext_vector_type(4))) float f32x4;
typedef __attribute__((ext_vector_type(8))) unsigned short u16x8;

__device__ __forceinline__ float hswish(float x) {
  return x * fminf(fmaxf(x + 3.f, 0.f), 6.f) * (1.f / 6.f);
}

__device__ __forceinline__ unsigned short f2bf(float f) {
  unsigned int u = __float_as_uint(f);
  u += 0x7fffu + ((u >> 16) & 1u);
  return (unsigned short)(u >> 16);
}

__device__ __forceinline__ void gload16(const void* g, void* l) {
  __builtin_amdgcn_global_load_lds(
      (const __attribute__((address_space(1))) void*)g,
      (__attribute__((address_space(3))) void*)l, 16, 0, 0);
}

// ---------------------------------------------------------------------------
// x [2048,32,512] fp32 -> bf16 (8 elems/thread)
// ---------------------------------------------------------------------------
__global__ __launch_bounds__(256) void x_to_bf16(const float* __restrict__ x,
                                                 unsigned short* __restrict__ xb) {
  long id = (long)(blockIdx.x * 256 + threadIdx.x) * 8;
  float4 a = *(const float4*)(x + id);
  float4 b = *(const float4*)(x + id + 4);
  u16x8 o;
  o[0] = f2bf(a.x); o[1] = f2bf(a.y); o[2] = f2bf(a.z); o[3] = f2bf(a.w);
  o[4] = f2bf(b.x); o[5] = f2bf(b.y); o[6] = f2bf(b.z); o[7] = f2bf(b.w);
  *(u16x8*)(xb + id) = o;
}

// ---------------------------------------------------------------------------
// conv weight w[co,ci,k] -> Bt[co][k*512+ci] bf16 (B^T layout, row=out unit)
// ---------------------------------------------------------------------------
__global__ __launch_bounds__(256) void conv_w_to_bt(const float* __restrict__ src,
                                                    unsigned short* __restrict__ dst,
                                                    int Kw, int rlshift) {
  int id = blockIdx.x * 256 + threadIdx.x;
  int co = id >> rlshift;
  int idx = id & ((1 << rlshift) - 1);
  int ci = idx & 511;
  int k = idx >> 9;
  dst[id] = f2bf(src[((co << 9) + ci) * Kw + k]);
}

// wq/wk/wv [in][out] -> Bqkv[o][in] bf16 (o in [0,1536)), bias concat
__global__ __launch_bounds__(256) void qkv_w_to_bt(
    const float* __restrict__ wq, const float* __restrict__ wk,
    const float* __restrict__ wv, const float* __restrict__ bq,
    const float* __restrict__ bk, const float* __restrict__ bv,
    unsigned short* __restrict__ Bt, float* __restrict__ bias) {
  int id = blockIdx.x * 256 + threadIdx.x;   // over 1536*512
  int o = id >> 9, i = id & 511;
  int oc = o & 511;
  const float* w = (o < 512) ? wq : (o < 1024) ? wk : wv;
  Bt[id] = f2bf(w[(i << 9) + oc]);
  if (i == 0) bias[o] = (o < 512) ? bq[oc] : (o < 1024) ? bk[oc] : bv[oc];
}

// ---------------------------------------------------------------------------
// bf16 MFMA GEMM: C[M,N] = A(view) @ Bt^T + bias.  Bt is [N][K] bf16.
// Tile 128x128xBK64, 4 waves, wave tile 64x64, mfma_f32_16x16x32_bf16.
// XCD-aware bijective block swizzle (T1): contiguous wg chunk per XCD,
// col-tile fastest within chunk (A-panel L2 reuse).
// ---------------------------------------------------------------------------
template <int MODE>
__global__ __launch_bounds__(256) void gemm_bt(
    const unsigned short* __restrict__ A, const unsigned short* __restrict__ Bt,
    float* __restrict__ C, const float* __restrict__ bias, int K, int ldc) {
  __shared__ unsigned short As[128 * 64];
  __shared__ unsigned short Bs[128 * 64];
  const int tid = threadIdx.x;
  const int wid = tid >> 6;
  const int lane = tid & 63;

  const int nwg = gridDim.x * gridDim.y;
  const int bid = blockIdx.x + gridDim.x * blockIdx.y;
  int xt, yt;
  if ((nwg & 7) == 0) {
    const int q = nwg >> 3;
    const int wg = (bid & 7) * q + (bid >> 3);
    xt = wg / gridDim.y;
    yt = wg % gridDim.y;
  } else {
    xt = blockIdx.x;
    yt = blockIdx.y;
  }
  const int r0 = xt * 128;
  const int c0 = yt * 128;

  const int wr = (wid >> 1) * 64;
  const int wc = (wid & 1) * 64;
  const int srow = lane >> 3;
  const int sslot = lane & 7;

  long aoffl[4], boffl[4];
  unsigned short* adst[4];
  unsigned short* bdst[4];
#pragma unroll
  for (int l = 0; l < 4; l++) {
    const int r = (wid * 4 + l) * 8 + srow;
    const int gr = r0 + r;
    long ao;
    if (MODE == 0)      ao = (long)(((gr >> 4) * 32) + ((gr & 15) << 1)) << 9;
    else if (MODE == 1) ao = (long)(((gr >> 3) * 32) + ((gr & 7) << 2)) << 9;
    else                ao = (long)gr * K;
    const int sw = (sslot ^ (r & 7)) << 3;
    aoffl[l] = ao + sw;
    boffl[l] = (long)(c0 + r) * K + sw;
    adst[l] = &As[(wid * 4 + l) * 8 * 64];
    bdst[l] = &Bs[(wid * 4 + l) * 8 * 64];
  }

  f32x4 acc[4][4];
#pragma unroll
  for (int m = 0; m < 4; m++)
#pragma unroll
    for (int n = 0; n < 4; n++) acc[m][n] = (f32x4){0.f, 0.f, 0.f, 0.f};

  const int fr = lane & 15;
  const int fq = lane >> 4;

  for (int kt = 0; kt < K; kt += 64) {
#pragma unroll
    for (int l = 0; l < 4; l++) {
      gload16(A + aoffl[l] + kt, adst[l]);
      gload16(Bt + boffl[l] + kt, bdst[l]);
    }
    __syncthreads();
#pragma unroll
    for (int ks = 0; ks < 2; ks++) {
      const int kq = ks * 4 + fq;
      bf16x8 af[4], bfr[4];
#pragma unroll
      for (int m = 0; m < 4; m++) {
        const int rr = wr + m * 16 + fr;
        af[m] = *(const bf16x8*)&As[rr * 64 + ((kq ^ (rr & 7)) << 3)];
      }
#pragma unroll
      for (int n = 0; n < 4; n++) {
        const int cc = wc + n * 16 + fr;
        bfr[n] = *(const bf16x8*)&Bs[cc * 64 + ((kq ^ (cc & 7)) << 3)];
      }
#pragma unroll
      for (int m = 0; m < 4; m++)
#pragma unroll
        for (int n = 0; n < 4; n++)
          acc[m][n] = __builtin_amdgcn_mfma_f32_16x16x32_bf16(
              af[m], bfr[n], acc[m][n], 0, 0, 0);
    }
    __syncthreads();
  }

  float bv[4];
#pragma unroll
  for (int n = 0; n < 4; n++) bv[n] = bias[c0 + wc + n * 16 + fr];

#pragma unroll
  for (int m = 0; m < 4; m++) {
#pragma unroll
    for (int j = 0; j < 4; j++) {
      const int gr = r0 + wr + m * 16 + fq * 4 + j;
      int crow;
      if (MODE == 0)      crow = (gr >> 4) * 24 + (gr & 15);
      else if (MODE == 1) crow = (gr >> 3) * 24 + 16 + (gr & 7);
      else                crow = gr;
      float* cp = C + (long)crow * ldc + c0 + wc + fr;
#pragma unroll
      for (int n = 0; n < 4; n++) cp[n * 16] = acc[m][n][j] + bv[n];
    }
  }
}

// ---------------------------------------------------------------------------
// LayerNorm over [TS, 512] jointly, per stock, in place on fbuf (fp32).
// ---------------------------------------------------------------------------
__global__ __launch_bounds__(256) void ln_kernel(
    float* __restrict__ fbuf,
    const float* __restrict__ g1, const float* __restrict__ b1,
    const float* __restrict__ g2, const float* __restrict__ b2) {
  const int n = blockIdx.x;
  const int tid = threadIdx.x;
  const int w = tid >> 6, lane = tid & 63;
  __shared__ float ws1[4], ws2[4];
  float* base = fbuf + (long)n * 24 * 512;

  {
    float4 v[8];
    float s = 0.f, sq = 0.f;
#pragma unroll
    for (int i = 0; i < 8; i++) {
      v[i] = *(const float4*)(base + (tid + i * 256) * 4);
      s += v[i].x + v[i].y + v[i].z + v[i].w;
      sq += v[i].x * v[i].x + v[i].y * v[i].y + v[i].z * v[i].z + v[i].w * v[i].w;
    }
    for (int d = 32; d; d >>= 1) { s += __shfl_down(s, d); sq += __shfl_down(sq, d); }
    if (lane == 0) { ws1[w] = s; ws2[w] = sq; }
    __syncthreads();
    float fs = ws1[0] + ws1[1] + ws1[2] + ws1[3];
    float fq = ws2[0] + ws2[1] + ws2[2] + ws2[3];
    float m = fs / 8192.f;
    float var = fq / 8192.f - m * m;
    float rstd = rsqrtf(var + 1e-5f);
#pragma unroll
    for (int i = 0; i < 8; i++) {
      int idx = (tid + i * 256) * 4;
      float4 gv = *(const float4*)(g1 + idx);
      float4 bvv = *(const float4*)(b1 + idx);
      float4 o;
      o.x = (v[i].x - m) * rstd * gv.x + bvv.x;
      o.y = (v[i].y - m) * rstd * gv.y + bvv.y;
      o.z = (v[i].z - m) * rstd * gv.z + bvv.z;
      o.w = (v[i].w - m) * rstd * gv.w + bvv.w;
      *(float4*)(base + idx) = o;
    }
    __syncthreads();
  }
  {
    float* base2 = base + 16 * 512;
    float4 v[4];
    float s = 0.f, sq = 0.f;
#pragma unroll
    for (int i = 0; i < 4; i++) {
      v[i] = *(const float4*)(base2 + (tid + i * 256) * 4);
      s += v[i].x + v[i].y + v[i].z + v[i].w;
      sq += v[i].x * v[i].x + v[i].y * v[i].y + v[i].z * v[i].z + v[i].w * v[i].w;
    }
    for (int d = 32; d; d >>= 1) { s += __shfl_down(s, d); sq += __shfl_down(sq, d); }
    if (lane == 0) { ws1[w] = s; ws2[w] = sq; }
    __syncthreads();
    float fs = ws1[0] + ws1[1] + ws1[2] + ws1[3];
    float fq = ws2[0] + ws2[1] + ws2[2] + ws2[3];
    float m = fs / 4096.f;
    float var = fq / 4096.f - m * m;
    float rstd = rsqrtf(var + 1e-5f);
#pragma unroll
    for (int i = 0; i < 4; i++) {
      int idx = (tid + i * 256) * 4;
      float4 gv = *(const float4*)(g2 + idx);
      float4 bvv = *(const float4*)(b2 + idx);
      float4 o;
      o.x = (v[i].x - m) * rstd * gv.x + bvv.x;
      o.y = (v[i].y - m) * rstd * gv.y + bvv.y;
      o.z = (v[i].z - m) * rstd * gv.z + bvv.z;
      o.w = (v[i].w - m) * rstd * gv.w + bvv.w;
      *(float4*)(base2 + idx) = o;
    }
  }
}

// ---------------------------------------------------------------------------
// w2c[t] = sum_{s>=t} W2[s][t] (t<56, else 0);  b2s = sum_s b2[s]
// (stage2 of TriU commutes with mean-pooling: only column sums are needed)
// ---------------------------------------------------------------------------
__global__ void triu_prep(const float* __restrict__ W2, const float* __restrict__ b2,
                          float* __restrict__ w2c, float* __restrict__ b2s) {
  int lane = threadIdx.x;   // 64 = 1 wave
  float s = 0.f;
  if (lane < 56)
    for (int r = lane; r < 56; r++) s += W2[r * 56 + lane];
  w2c[lane] = s;
  float b = (lane < 56) ? b2[lane] : 0.f;
  for (int d = 32; d; d >>= 1) b += __shfl_xor(b, d);
  if (lane == 0) b2s[0] = b;
}

// ---------------------------------------------------------------------------
// Fused TriU stage1 + hardswish + (stage2*pool collapsed to dot with w2c).
// One block per (stock, half). LDS 76KB -> 2 blocks/CU.
// ---------------------------------------------------------------------------
__global__ __launch_bounds__(256) void triu_pool(
    const float* __restrict__ x, const float* __restrict__ fbuf,
    const float* __restrict__ W1, const float* __restrict__ b1,
    const float* __restrict__ w2c, const float* __restrict__ b2s,
    float* __restrict__ pooled, unsigned short* __restrict__ pooledbf) {
  __shared__ float Z[56][256];
  __shared__ float W1t[56][64];   // W1t[t][s] = tril(W1)[s][t], s padded to 64
  __shared__ float b1s[64], w2cs[64];
  __shared__ float pp[4][256];

  const int tid = threadIdx.x;
  const int n = blockIdx.x >> 1;
  const int half = blockIdx.x & 1;
  const int cb = half * 256;

  for (int idx = tid; idx < 56 * 64; idx += 256) {
    int t = idx >> 6, s = idx & 63;
    W1t[t][s] = (s < 56 && t <= s) ? W1[s * 56 + t] : 0.f;
  }
  if (tid < 64) {
    b1s[tid] = (tid < 56) ? b1[tid] : 0.f;
    w2cs[tid] = w2c[tid];
  }
  for (int slot = tid; slot < 56 * 64; slot += 256) {
    int t = slot >> 6, cq = slot & 63;
    const float* src = (t < 32)
        ? (x + ((long)(n * 32 + t) * 512 + cb + cq * 4))
        : (fbuf + ((long)(n * 24 + (t - 32)) * 512 + cb + cq * 4));
    *(float4*)&Z[t][cq * 4] = *(const float4*)src;
  }
  __syncthreads();

  const int cg = tid >> 2, sg = tid & 3;   // cg in [0,64), sg in [0,4)
  const int c0 = cg * 4, s0 = sg * 16;

  float4 acc[16];
#pragma unroll
  for (int j = 0; j < 16; j++) acc[j] = make_float4(0.f, 0.f, 0.f, 0.f);

  // stage 1: h1[c, s] = sum_t Z[t][c] * W1t[t][s]
  for (int t = 0; t < 56; t++) {
    float4 a = *(const float4*)&Z[t][c0];
#pragma unroll
    for (int j4 = 0; j4 < 4; j4++) {
      float4 wv = *(const float4*)&W1t[t][s0 + j4 * 4];
      float wr[4] = {wv.x, wv.y, wv.z, wv.w};
#pragma unroll
      for (int jj = 0; jj < 4; jj++) {
        int j = j4 * 4 + jj;
        acc[j].x = fmaf(a.x, wr[jj], acc[j].x);
        acc[j].y = fmaf(a.y, wr[jj], acc[j].y);
        acc[j].z = fmaf(a.z, wr[jj], acc[j].z);
        acc[j].w = fmaf(a.w, wr[jj], acc[j].w);
      }
    }
  }

  // epilogue: ps[c] = sum_s hswish(h1[c,s] + b1[s]) * w2c[s]
  // (pads s>=56 contribute 0: acc=0, b1s=0 -> hswish(0)=0; w2cs=0)
  float4 ps = make_float4(0.f, 0.f, 0.f, 0.f);
#pragma unroll
  for (int j = 0; j < 16; j++) {
    int s = s0 + j;
    float bs = b1s[s];
    float wc = w2cs[s];
    ps.x = fmaf(hswish(acc[j].x + bs), wc, ps.x);
    ps.y = fmaf(hswish(acc[j].y + bs), wc, ps.y);
    ps.z = fmaf(hswish(acc[j].z + bs), wc, ps.z);
    ps.w = fmaf(hswish(acc[j].w + bs), wc, ps.w);
  }
  *(float4*)&pp[sg][c0] = ps;
  __syncthreads();
  int c = tid;
  float tot = pp[0][c] + pp[1][c] + pp[2][c] + pp[3][c];
  float pv = (tot + b2s[0]) * (1.f / 56.f);
  pooled[(long)n * 512 + cb + c] = pv;
  pooledbf[(long)n * 512 + cb + c] = f2bf(pv);
}

// ---------------------------------------------------------------------------
// Industry binning
// ---------------------------------------------------------------------------
__global__ void binzero(int* counts, int* cursor) {
  int i = threadIdx.x;
  if (i < 64) { counts[i] = 0; cursor[i] = 0; }
}
__global__ void bincount(const int* __restrict__ ids, int* counts) {
  int n = blockIdx.x * 256 + threadIdx.x;
  if (n < NST) atomicAdd(&counts[ids[n]], 1);
}
__global__ void binscan(const int* __restrict__ counts, int* offs) {
  int lane = threadIdx.x;
  int incl = counts[lane];
  for (int d = 1; d < 64; d <<= 1) {
    int u = __shfl_up(incl, d);
    if (lane >= d) incl += u;
  }
  offs[lane + 1] = incl;
  if (lane == 0) offs[0] = 0;
}
__global__ void binscatter(const int* __restrict__ ids, const int* __restrict__ offs,
                           int* cursor, int* perm) {
  int n = blockIdx.x * 256 + threadIdx.x;
  if (n < NST) {
    int g = ids[n];
    int pos = offs[g] + atomicAdd(&cursor[g], 1);
    perm[pos] = n;
  }
}

// ---------------------------------------------------------------------------
// Block-sparse attention over fused qkv buffer [N][1536] (q|k|v)
// ---------------------------------------------------------------------------
__global__ __launch_bounds__(256) void attn_kernel(
    const float* __restrict__ qkv, const int* __restrict__ offs,
    const int* __restrict__ perm, float* __restrict__ attnv) {
  const int g = blockIdx.x, h = blockIdx.y;
  const int off = offs[g];
  const int S = offs[g + 1] - off;
  const int w = threadIdx.x >> 6, lane = threadIdx.x & 63;
  __shared__ float pbuf[4][64];
  __shared__ int jbuf[4][64];

  for (int i = w; i < S; i += 4) {
    const int mi = perm[off + i];
    const float* qp = qkv + (long)mi * 1536 + h * 64;
    float m_run = -1e30f, l_run = 0.f, o_d = 0.f;
    for (int jb = 0; jb < S; jb += 64) {
      int jc = min(64, S - jb);
      int mj = (lane < jc) ? perm[off + jb + lane] : 0;
      float sc = -1e30f;
      if (lane < jc) {
        const float* kp = qkv + (long)mj * 1536 + 512 + h * 64;
        float a = 0.f;
#pragma unroll
        for (int d4 = 0; d4 < 16; d4++) {
          float4 qv = *(const float4*)(qp + d4 * 4);
          float4 kv = *(const float4*)(kp + d4 * 4);
          a += qv.x * kv.x + qv.y * kv.y + qv.z * kv.z + qv.w * kv.w;
        }
        sc = a * 0.125f;
      }
      float cm = sc;
      for (int d = 32; d; d >>= 1) cm = fmaxf(cm, __shfl_xor(cm, d));
      float m_new = fmaxf(m_run, cm);
      float resc = __expf(m_run - m_new);
      float p = (lane < jc) ? __expf(sc - m_new) : 0.f;
      float cs = p;
      for (int d = 32; d; d >>= 1) cs += __shfl_xor(cs, d);
      l_run = l_run * resc + cs;
      pbuf[w][lane] = p;
      jbuf[w][lane] = mj;
      float onew = o_d * resc;
      for (int j = 0; j < jc; j++) {
        float pj = pbuf[w][j];
        int mjj = jbuf[w][j];
        onew = fmaf(pj, qkv[(long)mjj * 1536 + 1024 + h * 64 + lane], onew);
      }
      o_d = onew;
      m_run = m_new;
    }
    attnv[(long)mi * 512 + h * 64 + lane] = o_d / l_run;
  }
}

// ---------------------------------------------------------------------------
__global__ void wowp_kernel(const float* __restrict__ wo, const float* __restrict__ wp,
                            const float* __restrict__ bo, const float* __restrict__ bp,
                            float* wowp, float* constbuf) {
  int w = threadIdx.x >> 6, lane = threadIdx.x & 63;
  int gw = blockIdx.x * 4 + w;
  for (int row = gw; row < 512; row += 32) {
    float partial = 0.f;
    for (int e = lane; e < 512; e += 64) partial += wo[(long)row * 512 + e] * wp[e];
    for (int d = 32; d; d >>= 1) partial += __shfl_xor(partial, d);
    if (lane == 0) wowp[row] = partial;
  }
  if (blockIdx.x == 0 && w == 0) {
    float partial = 0.f;
    for (int e = lane; e < 512; e += 64) partial += bo[e] * wp[e];
    for (int d = 32; d; d >>= 1) partial += __shfl_xor(partial, d);
    if (lane == 0) constbuf[0] = partial + bp[0];
  }
}

__global__ void final_kernel(const float* __restrict__ pooled,
                             const float* __restrict__ attnv,
                             const float* __restrict__ wp,
                             const float* __restrict__ wowp,
                             const float* __restrict__ constbuf,
                             float* __restrict__ out) {
  int w = threadIdx.x >> 6, lane = threadIdx.x & 63;
  int row = blockIdx.x * 4 + w;
  float partial = 0.f;
#pragma unroll
  for (int e8 = 0; e8 < 8; e8++) {
    int e = lane + e8 * 64;
    partial += pooled[(long)row * 512 + e] * wp[e] + attnv[(long)row * 512 + e] * wowp[e];
  }
  for (int d = 32; d; d >>= 1) partial += __shfl_xor(partial, d);
  if (lane == 0) out[row] = partial + constbuf[0];
}

// ---------------------------------------------------------------------------
extern "C" void kernel_launch(void* const* d_in, const int* in_sizes, int n_in,
                              void* d_out, int out_size, void* d_ws, size_t ws_size,
                              hipStream_t stream) {
  const float* x   = (const float*)d_in[0];
  const int*   ids = (const int*)d_in[1];
  const float* w1  = (const float*)d_in[2];
  const float* cb1 = (const float*)d_in[3];
  const float* w2  = (const float*)d_in[4];
  const float* cb2 = (const float*)d_in[5];
  const float* g1  = (const float*)d_in[6];
  const float* lb1 = (const float*)d_in[7];
  const float* g2  = (const float*)d_in[8];
  const float* lb2 = (const float*)d_in[9];
  const float* tw1 = (const float*)d_in[10];
  const float* tb1 = (const float*)d_in[11];
  const float* tw2 = (const float*)d_in[12];
  const float* tb2 = (const float*)d_in[13];
  const float* wq  = (const float*)d_in[14];
  const float* bq  = (const float*)d_in[15];
  const float* wk  = (const float*)d_in[16];
  const float* bk  = (const float*)d_in[17];
  const float* wv  = (const float*)d_in[18];
  const float* bv  = (const float*)d_in[19];
  const float* wo  = (const float*)d_in[20];
  const float* bo  = (const float*)d_in[21];
  const float* wp  = (const float*)d_in[22];
  const float* bp  = (const float*)d_in[23];
  float* out = (float*)d_out;

  char* ws = (char*)d_ws;
  size_t off = 0;
  auto alloc = [&](size_t bytes) {
    void* p = ws + off;
    off += (bytes + 255) & ~(size_t)255;
    return p;
  };
  unsigned short* xbf  = (unsigned short*)alloc((size_t)NST * 32 * 512 * 2);  // 67 MB
  unsigned short* B1b  = (unsigned short*)alloc((size_t)512 * 1024 * 2);
  unsigned short* B2b  = (unsigned short*)alloc((size_t)512 * 2048 * 2);
  unsigned short* Bqkv = (unsigned short*)alloc((size_t)1536 * 512 * 2);
  float* bqkv   = (float*)alloc(1536 * 4);
  float* fbuf   = (float*)alloc((size_t)NST * 24 * 512 * 4);                  // 100 MB
  float* pooled = (float*)alloc((size_t)NST * 512 * 4);
  unsigned short* pooledbf = (unsigned short*)alloc((size_t)NST * 512 * 2);
  float* qkvb   = (float*)alloc((size_t)NST * 1536 * 4);
  float* attnv  = (float*)alloc((size_t)NST * 512 * 4);
  float* wowp   = (float*)alloc(512 * 4);
  float* cbuf   = (float*)alloc(4);
  float* w2c    = (float*)alloc(64 * 4);
  float* b2s    = (float*)alloc(4);
  int* counts   = (int*)alloc(64 * 4);
  int* cursor   = (int*)alloc(64 * 4);
  int* offs     = (int*)alloc(65 * 4);
  int* perm     = (int*)alloc(NST * 4);

  // prep: conversions + weight transposes + binning + folded projections
  x_to_bf16<<<dim3(NST * 32 * 512 / (256 * 8)), 256, 0, stream>>>(x, xbf);
  conv_w_to_bt<<<dim3(512 * 1024 / 256), 256, 0, stream>>>(w1, B1b, 2, 10);
  conv_w_to_bt<<<dim3(512 * 2048 / 256), 256, 0, stream>>>(w2, B2b, 4, 11);
  qkv_w_to_bt<<<dim3(1536 * 512 / 256), 256, 0, stream>>>(wq, wk, wv, bq, bk, bv, Bqkv, bqkv);
  triu_prep<<<1, 64, 0, stream>>>(tw2, tb2, w2c, b2s);
  binzero<<<1, 64, 0, stream>>>(counts, cursor);
  bincount<<<8, 256, 0, stream>>>(ids, counts);
  binscan<<<1, 64, 0, stream>>>(counts, offs);
  binscatter<<<8, 256, 0, stream>>>(ids, offs, cursor, perm);
  wowp_kernel<<<8, 256, 0, stream>>>(wo, wp, bo, bp, wowp, cbuf);

  // conv1: M=32768 K=1024; conv2: M=16384 K=2048 (bf16 MFMA GEMMs on views)
  gemm_bt<0><<<dim3(256, 4), 256, 0, stream>>>(xbf, B1b, fbuf, cb1, 1024, 512);
  gemm_bt<1><<<dim3(128, 4), 256, 0, stream>>>(xbf, B2b, fbuf, cb2, 2048, 512);
  ln_kernel<<<NST, 256, 0, stream>>>(fbuf, g1, lb1, g2, lb2);
  triu_pool<<<NST * 2, 256, 0, stream>>>(x, fbuf, tw1, tb1, w2c, b2s, pooled, pooledbf);

  // fused q|k|v: M=2048 N=1536 K=512
  gemm_bt<2><<<dim3(16, 12), 256, 0, stream>>>(pooledbf, Bqkv, qkvb, bqkv, 512, 1536);

  attn_kernel<<<dim3(64, 8), 256, 0, stream>>>(qkvb, offs, perm, attnv);
  final_kernel<<<512, 256, 0, stream>>>(pooled, attnv, wp, wowp, cbuf, out);
}

// Round 4
// 713.704 us; speedup vs baseline: 2.4993x; 1.0580x over previous
//
#include <hip/hip_runtime.h>

#define NST 2048   // stocks

typedef __attribute__((ext_vector_type(8))) short bf16x8;
typedef __attribute__((ext_vector_type(4))) float f32x4;
typedef __attribute__((ext_vector_type(8))) unsigned short u16x8;

__device__ __forceinline__ float hswish(float x) {
  return x * fminf(fmaxf(x + 3.f, 0.f), 6.f) * (1.f / 6.f);
}

__device__ __forceinline__ unsigned short f2bf(float f) {
  unsigned int u = __float_as_uint(f);
  u += 0x7fffu + ((u >> 16) & 1u);
  return (unsigned short)(u >> 16);
}

__device__ __forceinline__ float bf2f(unsigned short b) {
  return __uint_as_float(((unsigned int)b) << 16);
}

__device__ __forceinline__ void gload16(const void* g, void* l) {
  __builtin_amdgcn_global_load_lds(
      (const __attribute__((address_space(1))) void*)g,
      (__attribute__((address_space(3))) void*)l, 16, 0, 0);
}

// ---------------------------------------------------------------------------
// x [2048,32,512] fp32 -> xbf [n][t][c] bf16  AND  xT [n][c][32] bf16.
// One block per stock; LDS tile transpose (row pad 520 kills bank conflicts).
// ---------------------------------------------------------------------------
__global__ __launch_bounds__(256) void x_prep(const float* __restrict__ x,
                                              unsigned short* __restrict__ xbf,
                                              unsigned short* __restrict__ xT) {
  __shared__ unsigned short T[32 * 520];
  const int n = blockIdx.x;
  const int tid = threadIdx.x;
  const float* xn = x + (long)n * 16384;
  unsigned short* xbn = xbf + (long)n * 16384;

#pragma unroll
  for (int i = 0; i < 16; i++) {
    int id = tid + i * 256;          // float4 chunk over 16384 floats
    int flat = id * 4;
    float4 v = *(const float4*)(xn + flat);
    short4 o;
    o.x = (short)f2bf(v.x); o.y = (short)f2bf(v.y);
    o.z = (short)f2bf(v.z); o.w = (short)f2bf(v.w);
    *(short4*)(xbn + flat) = o;
    int t = flat >> 9, c = flat & 511;
    *(short4*)&T[t * 520 + c] = o;
  }
  __syncthreads();

#pragma unroll
  for (int r = 0; r < 2; r++) {
    int c = tid + r * 256;
    unsigned short* dst = xT + ((long)n * 512 + c) * 32;
#pragma unroll
    for (int q = 0; q < 4; q++) {
      short4 o;
      o.x = (short)T[(q * 8 + 0) * 520 + c];
      o.y = (short)T[(q * 8 + 1) * 520 + c];
      o.z = (short)T[(q * 8 + 2) * 520 + c];
      o.w = (short)T[(q * 8 + 3) * 520 + c];
      short4 p;
      p.x = (short)T[(q * 8 + 4) * 520 + c];
      p.y = (short)T[(q * 8 + 5) * 520 + c];
      p.z = (short)T[(q * 8 + 6) * 520 + c];
      p.w = (short)T[(q * 8 + 7) * 520 + c];
      *(short4*)(dst + q * 8) = o;
      *(short4*)(dst + q * 8 + 4) = p;
    }
  }
}

// ---------------------------------------------------------------------------
// conv weight w[co,ci,k] -> Bt[co][k*512+ci] bf16
// ---------------------------------------------------------------------------
__global__ __launch_bounds__(256) void conv_w_to_bt(const float* __restrict__ src,
                                                    unsigned short* __restrict__ dst,
                                                    int Kw, int rlshift) {
  int id = blockIdx.x * 256 + threadIdx.x;
  int co = id >> rlshift;
  int idx = id & ((1 << rlshift) - 1);
  int ci = idx & 511;
  int k = idx >> 9;
  dst[id] = f2bf(src[((co << 9) + ci) * Kw + k]);
}

// wq/wk/wv [in][out] -> Bqkv[o][in] bf16 (o in [0,1536)), bias concat
__global__ __launch_bounds__(256) void qkv_w_to_bt(
    const float* __restrict__ wq, const float* __restrict__ wk,
    const float* __restrict__ wv, const float* __restrict__ bq,
    const float* __restrict__ bk, const float* __restrict__ bv,
    unsigned short* __restrict__ Bt, float* __restrict__ bias) {
  int id = blockIdx.x * 256 + threadIdx.x;
  int o = id >> 9, i = id & 511;
  int oc = o & 511;
  const float* w = (o < 512) ? wq : (o < 1024) ? wk : wv;
  Bt[id] = f2bf(w[(i << 9) + oc]);
  if (i == 0) bias[o] = (o < 512) ? bq[oc] : (o < 1024) ? bk[oc] : bv[oc];
}

// ---------------------------------------------------------------------------
// TriU prep: W1bf[s][t] = bf16 tril(W1) zero-padded to 64x64;
// w2cp[t] = sum_{s>=t} W2[s][t] (0-padded); b1p (0-padded); b2s = sum b2.
// ---------------------------------------------------------------------------
__global__ __launch_bounds__(256) void triu_prep(
    const float* __restrict__ W1, const float* __restrict__ b1,
    const float* __restrict__ W2, const float* __restrict__ b2,
    unsigned short* __restrict__ W1bf, float* __restrict__ w2cp,
    float* __restrict__ b1p, float* __restrict__ b2s) {
  int tid = threadIdx.x;
#pragma unroll
  for (int i = 0; i < 16; i++) {
    int id = tid + i * 256;          // over 4096
    int s = id >> 6, t = id & 63;
    float v = (s < 56 && t < 56 && t <= s) ? W1[s * 56 + t] : 0.f;
    W1bf[id] = f2bf(v);
  }
  if (tid < 64) {
    float sum = 0.f;
    if (tid < 56)
      for (int r = tid; r < 56; r++) sum += W2[r * 56 + tid];
    w2cp[tid] = sum;
    b1p[tid] = (tid < 56) ? b1[tid] : 0.f;
  }
  if (tid == 0) {
    float b = 0.f;
    for (int s = 0; s < 56; s++) b += b2[s];
    b2s[0] = b;
  }
}

// ---------------------------------------------------------------------------
// bf16 MFMA GEMM.  Bt is [N][K] bf16.  Tile 128x128x64, 4 waves.
// MODE 0/1 (convs): output -> fT[n][c][32] bf16 (t-contiguous, packed 8B).
//   MODE 0: A-row gr -> xbf+((gr>>4)*32+((gr&15)<<1))*512; fT entry = gr&15
//   MODE 1: A-row gr -> xbf+((gr>>3)*32+((gr&7)<<2))*512; fT entry = 16+(gr&7)
// MODE 2 (qkv): plain rows, fp32 C[M,ldc].
// ---------------------------------------------------------------------------
template <int MODE>
__global__ __launch_bounds__(256) void gemm_bt(
    const unsigned short* __restrict__ A, const unsigned short* __restrict__ Bt,
    float* __restrict__ C, unsigned short* __restrict__ fT,
    const float* __restrict__ bias, int K, int ldc) {
  __shared__ unsigned short As[128 * 64];
  __shared__ unsigned short Bs[128 * 64];
  const int tid = threadIdx.x;
  const int wid = tid >> 6;
  const int lane = tid & 63;
  const int r0 = blockIdx.x * 128;
  const int c0 = blockIdx.y * 128;
  const int wr = (wid >> 1) * 64;
  const int wc = (wid & 1) * 64;
  const int srow = lane >> 3;
  const int sslot = lane & 7;

  long aoffl[4], boffl[4];
  unsigned short* adst[4];
  unsigned short* bdst[4];
#pragma unroll
  for (int l = 0; l < 4; l++) {
    const int r = (wid * 4 + l) * 8 + srow;
    const int gr = r0 + r;
    long ao;
    if (MODE == 0)      ao = (long)(((gr >> 4) * 32) + ((gr & 15) << 1)) << 9;
    else if (MODE == 1) ao = (long)(((gr >> 3) * 32) + ((gr & 7) << 2)) << 9;
    else                ao = (long)gr * K;
    const int sw = (sslot ^ (r & 7)) << 3;
    aoffl[l] = ao + sw;
    boffl[l] = (long)(c0 + r) * K + sw;
    adst[l] = &As[(wid * 4 + l) * 8 * 64];
    bdst[l] = &Bs[(wid * 4 + l) * 8 * 64];
  }

  f32x4 acc[4][4];
#pragma unroll
  for (int m = 0; m < 4; m++)
#pragma unroll
    for (int n = 0; n < 4; n++) acc[m][n] = (f32x4){0.f, 0.f, 0.f, 0.f};

  const int fr = lane & 15;
  const int fq = lane >> 4;

  for (int kt = 0; kt < K; kt += 64) {
#pragma unroll
    for (int l = 0; l < 4; l++) {
      gload16(A + aoffl[l] + kt, adst[l]);
      gload16(Bt + boffl[l] + kt, bdst[l]);
    }
    __syncthreads();
#pragma unroll
    for (int ks = 0; ks < 2; ks++) {
      const int kq = ks * 4 + fq;
      bf16x8 af[4], bfr[4];
#pragma unroll
      for (int m = 0; m < 4; m++) {
        const int rr = wr + m * 16 + fr;
        af[m] = *(const bf16x8*)&As[rr * 64 + ((kq ^ (rr & 7)) << 3)];
      }
#pragma unroll
      for (int n = 0; n < 4; n++) {
        const int cc = wc + n * 16 + fr;
        bfr[n] = *(const bf16x8*)&Bs[cc * 64 + ((kq ^ (cc & 7)) << 3)];
      }
#pragma unroll
      for (int m = 0; m < 4; m++)
#pragma unroll
        for (int n = 0; n < 4; n++)
          acc[m][n] = __builtin_amdgcn_mfma_f32_16x16x32_bf16(
              af[m], bfr[n], acc[m][n], 0, 0, 0);
    }
    __syncthreads();
  }

  float bv[4];
#pragma unroll
  for (int n = 0; n < 4; n++) bv[n] = bias[c0 + wc + n * 16 + fr];

  if (MODE == 2) {
#pragma unroll
    for (int m = 0; m < 4; m++)
#pragma unroll
      for (int j = 0; j < 4; j++) {
        const int gr = r0 + wr + m * 16 + fq * 4 + j;
        float* cp = C + (long)gr * ldc + c0 + wc + fr;
#pragma unroll
        for (int n = 0; n < 4; n++) cp[n * 16] = acc[m][n][j] + bv[n];
      }
  } else {
#pragma unroll
    for (int m = 0; m < 4; m++) {
      const int gr = r0 + wr + m * 16 + fq * 4;   // j=0 row; j contiguous in ts
      int nst, e0;
      if (MODE == 0) { nst = gr >> 4; e0 = gr & 15; }
      else           { nst = gr >> 3; e0 = 16 + (gr & 7); }
#pragma unroll
      for (int n = 0; n < 4; n++) {
        const int cc = c0 + wc + n * 16 + fr;
        short4 o;
        o.x = (short)f2bf(acc[m][n][0] + bv[n]);
        o.y = (short)f2bf(acc[m][n][1] + bv[n]);
        o.z = (short)f2bf(acc[m][n][2] + bv[n]);
        o.w = (short)f2bf(acc[m][n][3] + bv[n]);
        *(short4*)(fT + ((long)(nst * 512 + cc) * 32 + e0)) = o;
      }
    }
  }
}

// ---------------------------------------------------------------------------
// LayerNorm in place on fT[n][c][32] bf16: entries 0..15 = f1 (stats over
// 8192), 16..23 = f2 (stats over 4096), 24..31 zeroed (Zt pad).
// g1 is [16][512] (ts-major), g2 [8][512].
// ---------------------------------------------------------------------------
__global__ __launch_bounds__(256) void ln_fT(
    unsigned short* __restrict__ fT,
    const float* __restrict__ g1, const float* __restrict__ b1,
    const float* __restrict__ g2, const float* __restrict__ b2) {
  const int n = blockIdx.x;
  const int tid = threadIdx.x;
  const int w = tid >> 6, lane = tid & 63;
  __shared__ float red[4][4];
  unsigned short* base = fT + (long)n * 16384;

  u16x8 ch[8];
  float s1 = 0.f, q1 = 0.f, s2 = 0.f, q2 = 0.f;
#pragma unroll
  for (int i = 0; i < 8; i++) {
    int id = tid + i * 256;        // u16x8 chunk over [c][q]
    int qq = id & 3;
    if (qq != 3) {
      u16x8 v = *(const u16x8*)(base + (long)id * 8);
      ch[i] = v;
      float fs = 0.f, fq = 0.f;
#pragma unroll
      for (int j = 0; j < 8; j++) {
        float f = bf2f(v[j]);
        fs += f; fq += f * f;
      }
      if (qq < 2) { s1 += fs; q1 += fq; } else { s2 += fs; q2 += fq; }
    }
  }
  for (int d = 32; d; d >>= 1) {
    s1 += __shfl_down(s1, d); q1 += __shfl_down(q1, d);
    s2 += __shfl_down(s2, d); q2 += __shfl_down(q2, d);
  }
  if (lane == 0) { red[w][0] = s1; red[w][1] = q1; red[w][2] = s2; red[w][3] = q2; }
  __syncthreads();
  float S1 = red[0][0] + red[1][0] + red[2][0] + red[3][0];
  float Q1 = red[0][1] + red[1][1] + red[2][1] + red[3][1];
  float S2 = red[0][2] + red[1][2] + red[2][2] + red[3][2];
  float Q2 = red[0][3] + red[1][3] + red[2][3] + red[3][3];
  float m1 = S1 / 8192.f, v1 = Q1 / 8192.f - m1 * m1;
  float r1 = rsqrtf(v1 + 1e-5f);
  float m2 = S2 / 4096.f, v2 = Q2 / 4096.f - m2 * m2;
  float r2 = rsqrtf(v2 + 1e-5f);

#pragma unroll
  for (int i = 0; i < 8; i++) {
    int id = tid + i * 256;
    int qq = id & 3, c = id >> 2;
    u16x8 o;
    if (qq == 3) {
#pragma unroll
      for (int j = 0; j < 8; j++) o[j] = 0;
    } else {
      float m = (qq < 2) ? m1 : m2;
      float r = (qq < 2) ? r1 : r2;
#pragma unroll
      for (int j = 0; j < 8; j++) {
        float g, b;
        if (qq < 2) { int ts = qq * 8 + j; g = g1[ts * 512 + c]; b = b1[ts * 512 + c]; }
        else        { g = g2[j * 512 + c]; b = b2[j * 512 + c]; }
        float f = bf2f(ch[i][j]);
        o[j] = f2bf((f - m) * r * g + b);
      }
    }
    *(u16x8*)(base + (long)id * 8) = o;
  }
}

// ---------------------------------------------------------------------------
// TriU stage1 via bf16 MFMA + hardswish + folded stage2*pool epilogue.
// One block per stock, 8 waves; wave w owns channels [w*64, w*64+64).
// Zt[c][64] bf16 in LDS (XOR slot-swizzle), staged from xT|fT rows which
// are t-contiguous per channel (pre-swizzled global source, linear LDS dest).
// ---------------------------------------------------------------------------
__global__ __launch_bounds__(512, 4) void triu_pool(
    const unsigned short* __restrict__ xT, const unsigned short* __restrict__ fT,
    const unsigned short* __restrict__ W1bf, const float* __restrict__ b1p,
    const float* __restrict__ w2cp, const float* __restrict__ b2s,
    float* __restrict__ pooled, unsigned short* __restrict__ pooledbf) {
  __shared__ unsigned short Zt[512 * 64];   // 64 KB
  const int tid = threadIdx.x;
  const int wid = tid >> 6;
  const int lane = tid & 63;
  const int n = blockIdx.x;
  const int fr = lane & 15;
  const int fq = lane >> 4;

  const unsigned short* xTn = xT + (long)n * 16384;
  const unsigned short* fTn = fT + (long)n * 16384;

  // stage this wave's 64 channel-rows (8 instrs x 8 rows)
#pragma unroll
  for (int cb = 0; cb < 8; cb++) {
    const int cbase = wid * 64 + cb * 8;
    const int c = cbase + (lane >> 3);
    const int slot = lane & 7;
    const int slotp = slot ^ (c & 7);
    const unsigned short* src = (slotp < 4)
        ? (xTn + c * 32 + slotp * 8)
        : (fTn + c * 32 + (slotp - 4) * 8);
    gload16(src, &Zt[cbase * 64]);
  }
  __syncthreads();

  // A fragments: W1bf rows (s), t-contiguous
  bf16x8 afr[4][2];
#pragma unroll
  for (int m = 0; m < 4; m++)
#pragma unroll
    for (int ks = 0; ks < 2; ks++)
      afr[m][ks] = *(const bf16x8*)(W1bf + (m * 16 + fr) * 64 + ks * 32 + fq * 8);

  f32x4 acc[4][4];   // [m(s-tile)][nn(c-tile)]
#pragma unroll
  for (int m = 0; m < 4; m++)
#pragma unroll
    for (int nn = 0; nn < 4; nn++) acc[m][nn] = (f32x4){0.f, 0.f, 0.f, 0.f};

#pragma unroll
  for (int nn = 0; nn < 4; nn++) {
    const int c = wid * 64 + nn * 16 + fr;
#pragma unroll
    for (int ks = 0; ks < 2; ks++) {
      const int slot = (ks * 4 + fq) ^ (c & 7);
      bf16x8 bfrag = *(const bf16x8*)&Zt[c * 64 + slot * 8];
#pragma unroll
      for (int m = 0; m < 4; m++)
        acc[m][nn] = __builtin_amdgcn_mfma_f32_16x16x32_bf16(
            afr[m][ks], bfrag, acc[m][nn], 0, 0, 0);
    }
  }

  // epilogue: per lane holds h1[s = m*16+fq*4+j][c = wid*64+nn*16+fr]
  float b1r[16], w2r[16];
#pragma unroll
  for (int m = 0; m < 4; m++)
#pragma unroll
    for (int j = 0; j < 4; j++) {
      int s = m * 16 + fq * 4 + j;
      b1r[m * 4 + j] = b1p[s];
      w2r[m * 4 + j] = w2cp[s];
    }
  const float b2sum = b2s[0];

#pragma unroll
  for (int nn = 0; nn < 4; nn++) {
    float cs = 0.f;
#pragma unroll
    for (int m = 0; m < 4; m++)
#pragma unroll
      for (int j = 0; j < 4; j++)
        cs = fmaf(hswish(acc[m][nn][j] + b1r[m * 4 + j]), w2r[m * 4 + j], cs);
    cs += __shfl_xor(cs, 16);
    cs += __shfl_xor(cs, 32);
    if (fq == 0) {
      const int c = wid * 64 + nn * 16 + fr;
      float pv = (cs + b2sum) * (1.f / 56.f);
      pooled[(long)n * 512 + c] = pv;
      pooledbf[(long)n * 512 + c] = f2bf(pv);
    }
  }
}

// ---------------------------------------------------------------------------
// Industry binning
// ---------------------------------------------------------------------------
__global__ void binzero(int* counts, int* cursor) {
  int i = threadIdx.x;
  if (i < 64) { counts[i] = 0; cursor[i] = 0; }
}
__global__ void bincount(const int* __restrict__ ids, int* counts) {
  int n = blockIdx.x * 256 + threadIdx.x;
  if (n < NST) atomicAdd(&counts[ids[n]], 1);
}
__global__ void binscan(const int* __restrict__ counts, int* offs) {
  int lane = threadIdx.x;
  int incl = counts[lane];
  for (int d = 1; d < 64; d <<= 1) {
    int u = __shfl_up(incl, d);
    if (lane >= d) incl += u;
  }
  offs[lane + 1] = incl;
  if (lane == 0) offs[0] = 0;
}
__global__ void binscatter(const int* __restrict__ ids, const int* __restrict__ offs,
                           int* cursor, int* perm) {
  int n = blockIdx.x * 256 + threadIdx.x;
  if (n < NST) {
    int g = ids[n];
    int pos = offs[g] + atomicAdd(&cursor[g], 1);
    perm[pos] = n;
  }
}

// ---------------------------------------------------------------------------
// Block-sparse attention over fused qkv buffer [N][1536] (q|k|v)
// ---------------------------------------------------------------------------
__global__ __launch_bounds__(256) void attn_kernel(
    const float* __restrict__ qkv, const int* __restrict__ offs,
    const int* __restrict__ perm, float* __restrict__ attnv) {
  const int g = blockIdx.x, h = blockIdx.y;
  const int off = offs[g];
  const int S = offs[g + 1] - off;
  const int w = threadIdx.x >> 6, lane = threadIdx.x & 63;
  __shared__ float pbuf[4][64];
  __shared__ int jbuf[4][64];

  for (int i = w; i < S; i += 4) {
    const int mi = perm[off + i];
    const float* qp = qkv + (long)mi * 1536 + h * 64;
    float m_run = -1e30f, l_run = 0.f, o_d = 0.f;
    for (int jb = 0; jb < S; jb += 64) {
      int jc = min(64, S - jb);
      int mj = (lane < jc) ? perm[off + jb + lane] : 0;
      float sc = -1e30f;
      if (lane < jc) {
        const float* kp = qkv + (long)mj * 1536 + 512 + h * 64;
        float a = 0.f;
#pragma unroll
        for (int d4 = 0; d4 < 16; d4++) {
          float4 qv = *(const float4*)(qp + d4 * 4);
          float4 kv = *(const float4*)(kp + d4 * 4);
          a += qv.x * kv.x + qv.y * kv.y + qv.z * kv.z + qv.w * kv.w;
        }
        sc = a * 0.125f;
      }
      float cm = sc;
      for (int d = 32; d; d >>= 1) cm = fmaxf(cm, __shfl_xor(cm, d));
      float m_new = fmaxf(m_run, cm);
      float resc = __expf(m_run - m_new);
      float p = (lane < jc) ? __expf(sc - m_new) : 0.f;
      float cs = p;
      for (int d = 32; d; d >>= 1) cs += __shfl_xor(cs, d);
      l_run = l_run * resc + cs;
      pbuf[w][lane] = p;
      jbuf[w][lane] = mj;
      float onew = o_d * resc;
      for (int j = 0; j < jc; j++) {
        float pj = pbuf[w][j];
        int mjj = jbuf[w][j];
        onew = fmaf(pj, qkv[(long)mjj * 1536 + 1024 + h * 64 + lane], onew);
      }
      o_d = onew;
      m_run = m_new;
    }
    attnv[(long)mi * 512 + h * 64 + lane] = o_d / l_run;
  }
}

// ---------------------------------------------------------------------------
__global__ void wowp_kernel(const float* __restrict__ wo, const float* __restrict__ wp,
                            const float* __restrict__ bo, const float* __restrict__ bp,
                            float* wowp, float* constbuf) {
  int w = threadIdx.x >> 6, lane = threadIdx.x & 63;
  int gw = blockIdx.x * 4 + w;
  for (int row = gw; row < 512; row += 32) {
    float partial = 0.f;
    for (int e = lane; e < 512; e += 64) partial += wo[(long)row * 512 + e] * wp[e];
    for (int d = 32; d; d >>= 1) partial += __shfl_xor(partial, d);
    if (lane == 0) wowp[row] = partial;
  }
  if (blockIdx.x == 0 && w == 0) {
    float partial = 0.f;
    for (int e = lane; e < 512; e += 64) partial += bo[e] * wp[e];
    for (int d = 32; d; d >>= 1) partial += __shfl_xor(partial, d);
    if (lane == 0) constbuf[0] = partial + bp[0];
  }
}

__global__ void final_kernel(const float* __restrict__ pooled,
                             const float* __restrict__ attnv,
                             const float* __restrict__ wp,
                             const float* __restrict__ wowp,
                             const float* __restrict__ constbuf,
                             float* __restrict__ out) {
  int w = threadIdx.x >> 6, lane = threadIdx.x & 63;
  int row = blockIdx.x * 4 + w;
  float partial = 0.f;
#pragma unroll
  for (int e8 = 0; e8 < 8; e8++) {
    int e = lane + e8 * 64;
    partial += pooled[(long)row * 512 + e] * wp[e] + attnv[(long)row * 512 + e] * wowp[e];
  }
  for (int d = 32; d; d >>= 1) partial += __shfl_xor(partial, d);
  if (lane == 0) out[row] = partial + constbuf[0];
}

// ---------------------------------------------------------------------------
extern "C" void kernel_launch(void* const* d_in, const int* in_sizes, int n_in,
                              void* d_out, int out_size, void* d_ws, size_t ws_size,
                              hipStream_t stream) {
  const float* x   = (const float*)d_in[0];
  const int*   ids = (const int*)d_in[1];
  const float* w1  = (const float*)d_in[2];
  const float* cb1 = (const float*)d_in[3];
  const float* w2  = (const float*)d_in[4];
  const float* cb2 = (const float*)d_in[5];
  const float* g1  = (const float*)d_in[6];
  const float* lb1 = (const float*)d_in[7];
  const float* g2  = (const float*)d_in[8];
  const float* lb2 = (const float*)d_in[9];
  const float* tw1 = (const float*)d_in[10];
  const float* tb1 = (const float*)d_in[11];
  const float* tw2 = (const float*)d_in[12];
  const float* tb2 = (const float*)d_in[13];
  const float* wq  = (const float*)d_in[14];
  const float* bq  = (const float*)d_in[15];
  const float* wk  = (const float*)d_in[16];
  const float* bk  = (const float*)d_in[17];
  const float* wv  = (const float*)d_in[18];
  const float* bv  = (const float*)d_in[19];
  const float* wo  = (const float*)d_in[20];
  const float* bo  = (const float*)d_in[21];
  const float* wp  = (const float*)d_in[22];
  const float* bp  = (const float*)d_in[23];
  float* out = (float*)d_out;

  char* ws = (char*)d_ws;
  size_t off = 0;
  auto alloc = [&](size_t bytes) {
    void* p = ws + off;
    off += (bytes + 255) & ~(size_t)255;
    return p;
  };
  unsigned short* xbf  = (unsigned short*)alloc((size_t)NST * 32 * 512 * 2);  // 67 MB
  unsigned short* xT   = (unsigned short*)alloc((size_t)NST * 512 * 32 * 2);  // 67 MB
  unsigned short* fT   = (unsigned short*)alloc((size_t)NST * 512 * 32 * 2);  // 67 MB
  unsigned short* B1b  = (unsigned short*)alloc((size_t)512 * 1024 * 2);
  unsigned short* B2b  = (unsigned short*)alloc((size_t)512 * 2048 * 2);
  unsigned short* Bqkv = (unsigned short*)alloc((size_t)1536 * 512 * 2);
  float* bqkv   = (float*)alloc(1536 * 4);
  unsigned short* W1bf = (unsigned short*)alloc(64 * 64 * 2);
  float* w2cp   = (float*)alloc(64 * 4);
  float* b1p    = (float*)alloc(64 * 4);
  float* b2s    = (float*)alloc(4);
  float* pooled = (float*)alloc((size_t)NST * 512 * 4);
  unsigned short* pooledbf = (unsigned short*)alloc((size_t)NST * 512 * 2);
  float* qkvb   = (float*)alloc((size_t)NST * 1536 * 4);
  float* attnv  = (float*)alloc((size_t)NST * 512 * 4);
  float* wowp   = (float*)alloc(512 * 4);
  float* cbuf   = (float*)alloc(4);
  int* counts   = (int*)alloc(64 * 4);
  int* cursor   = (int*)alloc(64 * 4);
  int* offs     = (int*)alloc(65 * 4);
  int* perm     = (int*)alloc(NST * 4);

  // prep
  x_prep<<<NST, 256, 0, stream>>>(x, xbf, xT);
  conv_w_to_bt<<<dim3(512 * 1024 / 256), 256, 0, stream>>>(w1, B1b, 2, 10);
  conv_w_to_bt<<<dim3(512 * 2048 / 256), 256, 0, stream>>>(w2, B2b, 4, 11);
  qkv_w_to_bt<<<dim3(1536 * 512 / 256), 256, 0, stream>>>(wq, wk, wv, bq, bk, bv, Bqkv, bqkv);
  triu_prep<<<1, 256, 0, stream>>>(tw1, tb1, tw2, tb2, W1bf, w2cp, b1p, b2s);
  binzero<<<1, 64, 0, stream>>>(counts, cursor);
  bincount<<<8, 256, 0, stream>>>(ids, counts);
  binscan<<<1, 64, 0, stream>>>(counts, offs);
  binscatter<<<8, 256, 0, stream>>>(ids, offs, cursor, perm);
  wowp_kernel<<<8, 256, 0, stream>>>(wo, wp, bo, bp, wowp, cbuf);

  // conv GEMMs -> fT bf16 (transposed per-channel layout)
  gemm_bt<0><<<dim3(256, 4), 256, 0, stream>>>(xbf, B1b, nullptr, fT, cb1, 1024, 0);
  gemm_bt<1><<<dim3(128, 4), 256, 0, stream>>>(xbf, B2b, nullptr, fT, cb2, 2048, 0);
  ln_fT<<<NST, 256, 0, stream>>>(fT, g1, lb1, g2, lb2);
  triu_pool<<<NST, 512, 0, stream>>>(xT, fT, W1bf, b1p, w2cp, b2s, pooled, pooledbf);

  // fused q|k|v: M=2048 N=1536 K=512
  gemm_bt<2><<<dim3(16, 12), 256, 0, stream>>>(pooledbf, Bqkv, qkvb, nullptr, bqkv, 512, 1536);

  attn_kernel<<<dim3(64, 8), 256, 0, stream>>>(qkvb, offs, perm, attnv);
  final_kernel<<<512, 256, 0, stream>>>(pooled, attnv, wp, wowp, cbuf, out);
}

// Round 6
// 606.848 us; speedup vs baseline: 2.9394x; 1.1761x over previous
//
#include <hip/hip_runtime.h>

#define NST 2048   // stocks

typedef __attribute__((ext_vector_type(8))) short bf16x8;
typedef __attribute__((ext_vector_type(4))) float f32x4;
typedef __attribute__((ext_vector_type(8))) unsigned short u16x8;

__device__ __forceinline__ float hswish(float x) {
  return x * fminf(fmaxf(x + 3.f, 0.f), 6.f) * (1.f / 6.f);
}

__device__ __forceinline__ unsigned short f2bf(float f) {
  unsigned int u = __float_as_uint(f);
  u += 0x7fffu + ((u >> 16) & 1u);
  return (unsigned short)(u >> 16);
}

__device__ __forceinline__ float bf2f(unsigned short b) {
  return __uint_as_float(((unsigned int)b) << 16);
}

__device__ __forceinline__ void gload16(const void* g, void* l) {
  __builtin_amdgcn_global_load_lds(
      (const __attribute__((address_space(1))) void*)g,
      (__attribute__((address_space(3))) void*)l, 16, 0, 0);
}

// ---------------------------------------------------------------------------
// x [2048,32,512] fp32 -> xbf [n][t][c] bf16  AND  xT [n][c][32] bf16.
// ---------------------------------------------------------------------------
__global__ __launch_bounds__(256) void x_prep(const float* __restrict__ x,
                                              unsigned short* __restrict__ xbf,
                                              unsigned short* __restrict__ xT) {
  __shared__ unsigned short T[32 * 520];
  const int n = blockIdx.x;
  const int tid = threadIdx.x;
  const float* xn = x + (long)n * 16384;
  unsigned short* xbn = xbf + (long)n * 16384;

#pragma unroll
  for (int i = 0; i < 16; i++) {
    int id = tid + i * 256;
    int flat = id * 4;
    float4 v = *(const float4*)(xn + flat);
    short4 o;
    o.x = (short)f2bf(v.x); o.y = (short)f2bf(v.y);
    o.z = (short)f2bf(v.z); o.w = (short)f2bf(v.w);
    *(short4*)(xbn + flat) = o;
    int t = flat >> 9, c = flat & 511;
    *(short4*)&T[t * 520 + c] = o;
  }
  __syncthreads();

#pragma unroll
  for (int r = 0; r < 2; r++) {
    int c = tid + r * 256;
    unsigned short* dst = xT + ((long)n * 512 + c) * 32;
#pragma unroll
    for (int q = 0; q < 4; q++) {
      short4 o;
      o.x = (short)T[(q * 8 + 0) * 520 + c];
      o.y = (short)T[(q * 8 + 1) * 520 + c];
      o.z = (short)T[(q * 8 + 2) * 520 + c];
      o.w = (short)T[(q * 8 + 3) * 520 + c];
      short4 p;
      p.x = (short)T[(q * 8 + 4) * 520 + c];
      p.y = (short)T[(q * 8 + 5) * 520 + c];
      p.z = (short)T[(q * 8 + 6) * 520 + c];
      p.w = (short)T[(q * 8 + 7) * 520 + c];
      *(short4*)(dst + q * 8) = o;
      *(short4*)(dst + q * 8 + 4) = p;
    }
  }
}

// ---------------------------------------------------------------------------
// conv weight w[co,ci,k] -> Bt[co][k*512+ci] bf16
// ---------------------------------------------------------------------------
__global__ __launch_bounds__(256) void conv_w_to_bt(const float* __restrict__ src,
                                                    unsigned short* __restrict__ dst,
                                                    int Kw, int rlshift) {
  int id = blockIdx.x * 256 + threadIdx.x;
  int co = id >> rlshift;
  int idx = id & ((1 << rlshift) - 1);
  int ci = idx & 511;
  int k = idx >> 9;
  dst[id] = f2bf(src[((co << 9) + ci) * Kw + k]);
}

// wq/wk/wv [in][out] -> Bqkv[o][in] bf16 (o in [0,1536)), bias concat
__global__ __launch_bounds__(256) void qkv_w_to_bt(
    const float* __restrict__ wq, const float* __restrict__ wk,
    const float* __restrict__ wv, const float* __restrict__ bq,
    const float* __restrict__ bk, const float* __restrict__ bv,
    unsigned short* __restrict__ Bt, float* __restrict__ bias) {
  int id = blockIdx.x * 256 + threadIdx.x;
  int o = id >> 9, i = id & 511;
  int oc = o & 511;
  const float* w = (o < 512) ? wq : (o < 1024) ? wk : wv;
  Bt[id] = f2bf(w[(i << 9) + oc]);
  if (i == 0) bias[o] = (o < 512) ? bq[oc] : (o < 1024) ? bk[oc] : bv[oc];
}

// ---------------------------------------------------------------------------
// TriU prep
// ---------------------------------------------------------------------------
__global__ __launch_bounds__(256) void triu_prep(
    const float* __restrict__ W1, const float* __restrict__ b1,
    const float* __restrict__ W2, const float* __restrict__ b2,
    unsigned short* __restrict__ W1bf, float* __restrict__ w2cp,
    float* __restrict__ b1p, float* __restrict__ b2s) {
  int tid = threadIdx.x;
#pragma unroll
  for (int i = 0; i < 16; i++) {
    int id = tid + i * 256;
    int s = id >> 6, t = id & 63;
    float v = (s < 56 && t < 56 && t <= s) ? W1[s * 56 + t] : 0.f;
    W1bf[id] = f2bf(v);
  }
  if (tid < 64) {
    float sum = 0.f;
    if (tid < 56)
      for (int r = tid; r < 56; r++) sum += W2[r * 56 + tid];
    w2cp[tid] = sum;
    b1p[tid] = (tid < 56) ? b1[tid] : 0.f;
  }
  if (tid == 0) {
    float b = 0.f;
    for (int s = 0; s < 56; s++) b += b2[s];
    b2s[0] = b;
  }
}

// ---------------------------------------------------------------------------
// bf16 MFMA GEMM (same as R4).
// ---------------------------------------------------------------------------
template <int MODE>
__global__ __launch_bounds__(256) void gemm_bt(
    const unsigned short* __restrict__ A, const unsigned short* __restrict__ Bt,
    float* __restrict__ C, unsigned short* __restrict__ fT,
    const float* __restrict__ bias, int K, int ldc) {
  __shared__ unsigned short As[128 * 64];
  __shared__ unsigned short Bs[128 * 64];
  const int tid = threadIdx.x;
  const int wid = tid >> 6;
  const int lane = tid & 63;
  const int r0 = blockIdx.x * 128;
  const int c0 = blockIdx.y * 128;
  const int wr = (wid >> 1) * 64;
  const int wc = (wid & 1) * 64;
  const int srow = lane >> 3;
  const int sslot = lane & 7;

  long aoffl[4], boffl[4];
  unsigned short* adst[4];
  unsigned short* bdst[4];
#pragma unroll
  for (int l = 0; l < 4; l++) {
    const int r = (wid * 4 + l) * 8 + srow;
    const int gr = r0 + r;
    long ao;
    if (MODE == 0)      ao = (long)(((gr >> 4) * 32) + ((gr & 15) << 1)) << 9;
    else if (MODE == 1) ao = (long)(((gr >> 3) * 32) + ((gr & 7) << 2)) << 9;
    else                ao = (long)gr * K;
    const int sw = (sslot ^ (r & 7)) << 3;
    aoffl[l] = ao + sw;
    boffl[l] = (long)(c0 + r) * K + sw;
    adst[l] = &As[(wid * 4 + l) * 8 * 64];
    bdst[l] = &Bs[(wid * 4 + l) * 8 * 64];
  }

  f32x4 acc[4][4];
#pragma unroll
  for (int m = 0; m < 4; m++)
#pragma unroll
    for (int n = 0; n < 4; n++) acc[m][n] = (f32x4){0.f, 0.f, 0.f, 0.f};

  const int fr = lane & 15;
  const int fq = lane >> 4;

  for (int kt = 0; kt < K; kt += 64) {
#pragma unroll
    for (int l = 0; l < 4; l++) {
      gload16(A + aoffl[l] + kt, adst[l]);
      gload16(Bt + boffl[l] + kt, bdst[l]);
    }
    __syncthreads();
#pragma unroll
    for (int ks = 0; ks < 2; ks++) {
      const int kq = ks * 4 + fq;
      bf16x8 af[4], bfr[4];
#pragma unroll
      for (int m = 0; m < 4; m++) {
        const int rr = wr + m * 16 + fr;
        af[m] = *(const bf16x8*)&As[rr * 64 + ((kq ^ (rr & 7)) << 3)];
      }
#pragma unroll
      for (int n = 0; n < 4; n++) {
        const int cc = wc + n * 16 + fr;
        bfr[n] = *(const bf16x8*)&Bs[cc * 64 + ((kq ^ (cc & 7)) << 3)];
      }
#pragma unroll
      for (int m = 0; m < 4; m++)
#pragma unroll
        for (int n = 0; n < 4; n++)
          acc[m][n] = __builtin_amdgcn_mfma_f32_16x16x32_bf16(
              af[m], bfr[n], acc[m][n], 0, 0, 0);
    }
    __syncthreads();
  }

  float bv[4];
#pragma unroll
  for (int n = 0; n < 4; n++) bv[n] = bias[c0 + wc + n * 16 + fr];

  if (MODE == 2) {
#pragma unroll
    for (int m = 0; m < 4; m++)
#pragma unroll
      for (int j = 0; j < 4; j++) {
        const int gr = r0 + wr + m * 16 + fq * 4 + j;
        float* cp = C + (long)gr * ldc + c0 + wc + fr;
#pragma unroll
        for (int n = 0; n < 4; n++) cp[n * 16] = acc[m][n][j] + bv[n];
      }
  } else {
#pragma unroll
    for (int m = 0; m < 4; m++) {
      const int gr = r0 + wr + m * 16 + fq * 4;
      int nst, e0;
      if (MODE == 0) { nst = gr >> 4; e0 = gr & 15; }
      else           { nst = gr >> 3; e0 = 16 + (gr & 7); }
#pragma unroll
      for (int n = 0; n < 4; n++) {
        const int cc = c0 + wc + n * 16 + fr;
        short4 o;
        o.x = (short)f2bf(acc[m][n][0] + bv[n]);
        o.y = (short)f2bf(acc[m][n][1] + bv[n]);
        o.z = (short)f2bf(acc[m][n][2] + bv[n]);
        o.w = (short)f2bf(acc[m][n][3] + bv[n]);
        *(short4*)(fT + ((long)(nst * 512 + cc) * 32 + e0)) = o;
      }
    }
  }
}

// ---------------------------------------------------------------------------
// LayerNorm in place on fT[n][c][32] bf16 (same as R4).
// ---------------------------------------------------------------------------
__global__ __launch_bounds__(256) void ln_fT(
    unsigned short* __restrict__ fT,
    const float* __restrict__ g1, const float* __restrict__ b1,
    const float* __restrict__ g2, const float* __restrict__ b2) {
  const int n = blockIdx.x;
  const int tid = threadIdx.x;
  const int w = tid >> 6, lane = tid & 63;
  __shared__ float red[4][4];
  unsigned short* base = fT + (long)n * 16384;

  u16x8 ch[8];
  float s1 = 0.f, q1 = 0.f, s2 = 0.f, q2 = 0.f;
#pragma unroll
  for (int i = 0; i < 8; i++) {
    int id = tid + i * 256;
    int qq = id & 3;
    if (qq != 3) {
      u16x8 v = *(const u16x8*)(base + (long)id * 8);
      ch[i] = v;
      float fs = 0.f, fq = 0.f;
#pragma unroll
      for (int j = 0; j < 8; j++) {
        float f = bf2f(v[j]);
        fs += f; fq += f * f;
      }
      if (qq < 2) { s1 += fs; q1 += fq; } else { s2 += fs; q2 += fq; }
    }
  }
  for (int d = 32; d; d >>= 1) {
    s1 += __shfl_down(s1, d); q1 += __shfl_down(q1, d);
    s2 += __shfl_down(s2, d); q2 += __shfl_down(q2, d);
  }
  if (lane == 0) { red[w][0] = s1; red[w][1] = q1; red[w][2] = s2; red[w][3] = q2; }
  __syncthreads();
  float S1 = red[0][0] + red[1][0] + red[2][0] + red[3][0];
  float Q1 = red[0][1] + red[1][1] + red[2][1] + red[3][1];
  float S2 = red[0][2] + red[1][2] + red[2][2] + red[3][2];
  float Q2 = red[0][3] + red[1][3] + red[2][3] + red[3][3];
  float m1 = S1 / 8192.f, v1 = Q1 / 8192.f - m1 * m1;
  float r1 = rsqrtf(v1 + 1e-5f);
  float m2 = S2 / 4096.f, v2 = Q2 / 4096.f - m2 * m2;
  float r2 = rsqrtf(v2 + 1e-5f);

#pragma unroll
  for (int i = 0; i < 8; i++) {
    int id = tid + i * 256;
    int qq = id & 3, c = id >> 2;
    u16x8 o;
    if (qq == 3) {
#pragma unroll
      for (int j = 0; j < 8; j++) o[j] = 0;
    } else {
      float m = (qq < 2) ? m1 : m2;
      float r = (qq < 2) ? r1 : r2;
#pragma unroll
      for (int j = 0; j < 8; j++) {
        float g, b;
        if (qq < 2) { int ts = qq * 8 + j; g = g1[ts * 512 + c]; b = b1[ts * 512 + c]; }
        else        { g = g2[j * 512 + c]; b = b2[j * 512 + c]; }
        float f = bf2f(ch[i][j]);
        o[j] = f2bf((f - m) * r * g + b);
      }
    }
    *(u16x8*)(base + (long)id * 8) = o;
  }
}

// ---------------------------------------------------------------------------
// TriU stage1 via bf16 MFMA + folded stage2*pool epilogue (same as R4).
// ---------------------------------------------------------------------------
__global__ __launch_bounds__(512, 4) void triu_pool(
    const unsigned short* __restrict__ xT, const unsigned short* __restrict__ fT,
    const unsigned short* __restrict__ W1bf, const float* __restrict__ b1p,
    const float* __restrict__ w2cp, const float* __restrict__ b2s,
    float* __restrict__ pooled, unsigned short* __restrict__ pooledbf) {
  __shared__ unsigned short Zt[512 * 64];
  const int tid = threadIdx.x;
  const int wid = tid >> 6;
  const int lane = tid & 63;
  const int n = blockIdx.x;
  const int fr = lane & 15;
  const int fq = lane >> 4;

  const unsigned short* xTn = xT + (long)n * 16384;
  const unsigned short* fTn = fT + (long)n * 16384;

#pragma unroll
  for (int cb = 0; cb < 8; cb++) {
    const int cbase = wid * 64 + cb * 8;
    const int c = cbase + (lane >> 3);
    const int slot = lane & 7;
    const int slotp = slot ^ (c & 7);
    const unsigned short* src = (slotp < 4)
        ? (xTn + c * 32 + slotp * 8)
        : (fTn + c * 32 + (slotp - 4) * 8);
    gload16(src, &Zt[cbase * 64]);
  }
  __syncthreads();

  bf16x8 afr[4][2];
#pragma unroll
  for (int m = 0; m < 4; m++)
#pragma unroll
    for (int ks = 0; ks < 2; ks++)
      afr[m][ks] = *(const bf16x8*)(W1bf + (m * 16 + fr) * 64 + ks * 32 + fq * 8);

  f32x4 acc[4][4];
#pragma unroll
  for (int m = 0; m < 4; m++)
#pragma unroll
    for (int nn = 0; nn < 4; nn++) acc[m][nn] = (f32x4){0.f, 0.f, 0.f, 0.f};

#pragma unroll
  for (int nn = 0; nn < 4; nn++) {
    const int c = wid * 64 + nn * 16 + fr;
#pragma unroll
    for (int ks = 0; ks < 2; ks++) {
      const int slot = (ks * 4 + fq) ^ (c & 7);
      bf16x8 bfrag = *(const bf16x8*)&Zt[c * 64 + slot * 8];
#pragma unroll
      for (int m = 0; m < 4; m++)
        acc[m][nn] = __builtin_amdgcn_mfma_f32_16x16x32_bf16(
            afr[m][ks], bfrag, acc[m][nn], 0, 0, 0);
    }
  }

  float b1r[16], w2r[16];
#pragma unroll
  for (int m = 0; m < 4; m++)
#pragma unroll
    for (int j = 0; j < 4; j++) {
      int s = m * 16 + fq * 4 + j;
      b1r[m * 4 + j] = b1p[s];
      w2r[m * 4 + j] = w2cp[s];
    }
  const float b2sum = b2s[0];

#pragma unroll
  for (int nn = 0; nn < 4; nn++) {
    float cs = 0.f;
#pragma unroll
    for (int m = 0; m < 4; m++)
#pragma unroll
      for (int j = 0; j < 4; j++)
        cs = fmaf(hswish(acc[m][nn][j] + b1r[m * 4 + j]), w2r[m * 4 + j], cs);
    cs += __shfl_xor(cs, 16);
    cs += __shfl_xor(cs, 32);
    if (fq == 0) {
      const int c = wid * 64 + nn * 16 + fr;
      float pv = (cs + b2sum) * (1.f / 56.f);
      pooled[(long)n * 512 + c] = pv;
      pooledbf[(long)n * 512 + c] = f2bf(pv);
    }
  }
}

// ---------------------------------------------------------------------------
// Industry binning
// ---------------------------------------------------------------------------
__global__ void binzero(int* counts, int* cursor) {
  int i = threadIdx.x;
  if (i < 64) { counts[i] = 0; cursor[i] = 0; }
}
__global__ void bincount(const int* __restrict__ ids, int* counts) {
  int n = blockIdx.x * 256 + threadIdx.x;
  if (n < NST) atomicAdd(&counts[ids[n]], 1);
}
__global__ void binscan(const int* __restrict__ counts, int* offs) {
  int lane = threadIdx.x;
  int incl = counts[lane];
  for (int d = 1; d < 64; d <<= 1) {
    int u = __shfl_up(incl, d);
    if (lane >= d) incl += u;
  }
  offs[lane + 1] = incl;
  if (lane == 0) offs[0] = 0;
}
__global__ void binscatter(const int* __restrict__ ids, const int* __restrict__ offs,
                           int* cursor, int* perm) {
  int n = blockIdx.x * 256 + threadIdx.x;
  if (n < NST) {
    int g = ids[n];
    int pos = offs[g] + atomicAdd(&cursor[g], 1);
    perm[pos] = n;
  }
}

// ---------------------------------------------------------------------------
// Block-sparse attention, LDS-staged & lane-parallel.
// Block = (industry g, head h), 4 waves. Fast path S<=128:
//   K rows staged to LDS padded 66 (2-way aliasing = free),
//   V rows staged 64-wide (consecutive = free), Q row in wave-local LDS.
//   Lane j holds score_j (2 chunks of 64); softmax via shfl reduce;
//   PV: lane d accumulates over j (broadcast P + row-read V).
// Fallback S>128: original global-memory path (correct for any S).
// ---------------------------------------------------------------------------
__global__ __launch_bounds__(256) void attn_kernel(
    const float* __restrict__ qkv, const int* __restrict__ offs,
    const int* __restrict__ perm, float* __restrict__ attnv) {
  const int g = blockIdx.x, h = blockIdx.y;
  const int off = offs[g];
  const int S = offs[g + 1] - off;
  const int tid = threadIdx.x;
  const int w = tid >> 6, lane = tid & 63;

  __shared__ float Ks[128 * 66];   // 33.8 KB
  __shared__ float Vs[128 * 64];   // 32.8 KB
  __shared__ float Ps[4][128];
  __shared__ float Qw[4][64];

  if (S <= 128) {
    // ---- stage K (pad 66) and V (64) ----
    for (int idx = tid; idx < S * 16; idx += 256) {
      const int row = idx >> 4, q4 = (idx & 15) * 4;
      const int mj = perm[off + row];
      const float* base = qkv + (long)mj * 1536 + h * 64 + q4;
      float4 kv = *(const float4*)(base + 512);
      float4 vv = *(const float4*)(base + 1024);
      float* kr = &Ks[row * 66 + q4];
      kr[0] = kv.x; kr[1] = kv.y; kr[2] = kv.z; kr[3] = kv.w;
      *(float4*)&Vs[row * 64 + q4] = vv;
    }
    __syncthreads();

    for (int i = w; i < S; i += 4) {
      const int mi = perm[off + i];
      const float qd = qkv[(long)mi * 1536 + h * 64 + lane];
      Qw[w][lane] = qd;   // wave-local; compiler inserts lgkmcnt wait

      float sc0 = -1e30f, sc1 = -1e30f;
      {
        const int j = lane;
        if (j < S) {
          float a = 0.f;
          const float* kr = &Ks[j * 66];
#pragma unroll
          for (int t = 0; t < 32; t++) {
            float2 k2 = *(const float2*)(kr + 2 * t);
            float2 q2 = *(const float2*)&Qw[w][2 * t];
            a = fmaf(q2.x, k2.x, a);
            a = fmaf(q2.y, k2.y, a);
          }
          sc0 = a * 0.125f;
        }
      }
      if (S > 64) {
        const int j = 64 + lane;
        if (j < S) {
          float a = 0.f;
          const float* kr = &Ks[j * 66];
#pragma unroll
          for (int t = 0; t < 32; t++) {
            float2 k2 = *(const float2*)(kr + 2 * t);
            float2 q2 = *(const float2*)&Qw[w][2 * t];
            a = fmaf(q2.x, k2.x, a);
            a = fmaf(q2.y, k2.y, a);
          }
          sc1 = a * 0.125f;
        }
      }
      float m = fmaxf(sc0, sc1);
      for (int d = 32; d; d >>= 1) m = fmaxf(m, __shfl_xor(m, d));
      float p0 = (lane < S) ? __expf(sc0 - m) : 0.f;
      float p1 = (64 + lane < S) ? __expf(sc1 - m) : 0.f;
      float l = p0 + p1;
      for (int d = 32; d; d >>= 1) l += __shfl_xor(l, d);
      Ps[w][lane] = p0;
      Ps[w][64 + lane] = p1;

      float o = 0.f;
      for (int j = 0; j < S; j++)
        o = fmaf(Ps[w][j], Vs[j * 64 + lane], o);
      attnv[(long)mi * 512 + h * 64 + lane] = o / l;
    }
  } else {
    // ---- fallback: original path, any S ----
    __shared__ float pbuf[4][64];
    __shared__ int jbuf[4][64];
    for (int i = w; i < S; i += 4) {
      const int mi = perm[off + i];
      const float* qp = qkv + (long)mi * 1536 + h * 64;
      float m_run = -1e30f, l_run = 0.f, o_d = 0.f;
      for (int jb = 0; jb < S; jb += 64) {
        int jc = min(64, S - jb);
        int mj = (lane < jc) ? perm[off + jb + lane] : 0;
        float sc = -1e30f;
        if (lane < jc) {
          const float* kp = qkv + (long)mj * 1536 + 512 + h * 64;
          float a = 0.f;
#pragma unroll
          for (int d4 = 0; d4 < 16; d4++) {
            float4 qv = *(const float4*)(qp + d4 * 4);
            float4 kv = *(const float4*)(kp + d4 * 4);
            a += qv.x * kv.x + qv.y * kv.y + qv.z * kv.z + qv.w * kv.w;
          }
          sc = a * 0.125f;
        }
        float cm = sc;
        for (int d = 32; d; d >>= 1) cm = fmaxf(cm, __shfl_xor(cm, d));
        float m_new = fmaxf(m_run, cm);
        float resc = __expf(m_run - m_new);
        float p = (lane < jc) ? __expf(sc - m_new) : 0.f;
        float cs = p;
        for (int d = 32; d; d >>= 1) cs += __shfl_xor(cs, d);
        l_run = l_run * resc + cs;
        pbuf[w][lane] = p;
        jbuf[w][lane] = mj;
        float onew = o_d * resc;
        for (int j = 0; j < jc; j++)
          onew = fmaf(pbuf[w][j], qkv[(long)jbuf[w][j] * 1536 + 1024 + h * 64 + lane], onew);
        o_d = onew;
        m_run = m_new;
      }
      attnv[(long)mi * 512 + h * 64 + lane] = o_d / l_run;
    }
  }
}

// ---------------------------------------------------------------------------
__global__ void wowp_kernel(const float* __restrict__ wo, const float* __restrict__ wp,
                            const float* __restrict__ bo, const float* __restrict__ bp,
                            float* wowp, float* constbuf) {
  int w = threadIdx.x >> 6, lane = threadIdx.x & 63;
  int gw = blockIdx.x * 4 + w;
  for (int row = gw; row < 512; row += 32) {
    float partial = 0.f;
    for (int e = lane; e < 512; e += 64) partial += wo[(long)row * 512 + e] * wp[e];
    for (int d = 32; d; d >>= 1) partial += __shfl_xor(partial, d);
    if (lane == 0) wowp[row] = partial;
  }
  if (blockIdx.x == 0 && w == 0) {
    float partial = 0.f;
    for (int e = lane; e < 512; e += 64) partial += bo[e] * wp[e];
    for (int d = 32; d; d >>= 1) partial += __shfl_xor(partial, d);
    if (lane == 0) constbuf[0] = partial + bp[0];
  }
}

__global__ void final_kernel(const float* __restrict__ pooled,
                             const float* __restrict__ attnv,
                             const float* __restrict__ wp,
                             const float* __restrict__ wowp,
                             const float* __restrict__ constbuf,
                             float* __restrict__ out) {
  int w = threadIdx.x >> 6, lane = threadIdx.x & 63;
  int row = blockIdx.x * 4 + w;
  float partial = 0.f;
#pragma unroll
  for (int e8 = 0; e8 < 8; e8++) {
    int e = lane + e8 * 64;
    partial += pooled[(long)row * 512 + e] * wp[e] + attnv[(long)row * 512 + e] * wowp[e];
  }
  for (int d = 32; d; d >>= 1) partial += __shfl_xor(partial, d);
  if (lane == 0) out[row] = partial + constbuf[0];
}

// ---------------------------------------------------------------------------
extern "C" void kernel_launch(void* const* d_in, const int* in_sizes, int n_in,
                              void* d_out, int out_size, void* d_ws, size_t ws_size,
                              hipStream_t stream) {
  const float* x   = (const float*)d_in[0];
  const int*   ids = (const int*)d_in[1];
  const float* w1  = (const float*)d_in[2];
  const float* cb1 = (const float*)d_in[3];
  const float* w2  = (const float*)d_in[4];
  const float* cb2 = (const float*)d_in[5];
  const float* g1  = (const float*)d_in[6];
  const float* lb1 = (const float*)d_in[7];
  const float* g2  = (const float*)d_in[8];
  const float* lb2 = (const float*)d_in[9];
  const float* tw1 = (const float*)d_in[10];
  const float* tb1 = (const float*)d_in[11];
  const float* tw2 = (const float*)d_in[12];
  const float* tb2 = (const float*)d_in[13];
  const float* wq  = (const float*)d_in[14];
  const float* bq  = (const float*)d_in[15];
  const float* wk  = (const float*)d_in[16];
  const float* bk  = (const float*)d_in[17];
  const float* wv  = (const float*)d_in[18];
  const float* bv  = (const float*)d_in[19];
  const float* wo  = (const float*)d_in[20];
  const float* bo  = (const float*)d_in[21];
  const float* wp  = (const float*)d_in[22];
  const float* bp  = (const float*)d_in[23];
  float* out = (float*)d_out;

  char* ws = (char*)d_ws;
  size_t off = 0;
  auto alloc = [&](size_t bytes) {
    void* p = ws + off;
    off += (bytes + 255) & ~(size_t)255;
    return p;
  };
  unsigned short* xbf  = (unsigned short*)alloc((size_t)NST * 32 * 512 * 2);
  unsigned short* xT   = (unsigned short*)alloc((size_t)NST * 512 * 32 * 2);
  unsigned short* fT   = (unsigned short*)alloc((size_t)NST * 512 * 32 * 2);
  unsigned short* B1b  = (unsigned short*)alloc((size_t)512 * 1024 * 2);
  unsigned short* B2b  = (unsigned short*)alloc((size_t)512 * 2048 * 2);
  unsigned short* Bqkv = (unsigned short*)alloc((size_t)1536 * 512 * 2);
  float* bqkv   = (float*)alloc(1536 * 4);
  unsigned short* W1bf = (unsigned short*)alloc(64 * 64 * 2);
  float* w2cp   = (float*)alloc(64 * 4);
  float* b1p    = (float*)alloc(64 * 4);
  float* b2s    = (float*)alloc(4);
  float* pooled = (float*)alloc((size_t)NST * 512 * 4);
  unsigned short* pooledbf = (unsigned short*)alloc((size_t)NST * 512 * 2);
  float* qkvb   = (float*)alloc((size_t)NST * 1536 * 4);
  float* attnv  = (float*)alloc((size_t)NST * 512 * 4);
  float* wowp   = (float*)alloc(512 * 4);
  float* cbuf   = (float*)alloc(4);
  int* counts   = (int*)alloc(64 * 4);
  int* cursor   = (int*)alloc(64 * 4);
  int* offs     = (int*)alloc(65 * 4);
  int* perm     = (int*)alloc(NST * 4);

  // prep
  x_prep<<<NST, 256, 0, stream>>>(x, xbf, xT);
  conv_w_to_bt<<<dim3(512 * 1024 / 256), 256, 0, stream>>>(w1, B1b, 2, 10);
  conv_w_to_bt<<<dim3(512 * 2048 / 256), 256, 0, stream>>>(w2, B2b, 4, 11);
  qkv_w_to_bt<<<dim3(1536 * 512 / 256), 256, 0, stream>>>(wq, wk, wv, bq, bk, bv, Bqkv, bqkv);
  triu_prep<<<1, 256, 0, stream>>>(tw1, tb1, tw2, tb2, W1bf, w2cp, b1p, b2s);
  binzero<<<1, 64, 0, stream>>>(counts, cursor);
  bincount<<<8, 256, 0, stream>>>(ids, counts);
  binscan<<<1, 64, 0, stream>>>(counts, offs);
  binscatter<<<8, 256, 0, stream>>>(ids, offs, cursor, perm);
  wowp_kernel<<<8, 256, 0, stream>>>(wo, wp, bo, bp, wowp, cbuf);

  // conv GEMMs -> fT bf16 (transposed per-channel layout)
  gemm_bt<0><<<dim3(256, 4), 256, 0, stream>>>(xbf, B1b, nullptr, fT, cb1, 1024, 0);
  gemm_bt<1><<<dim3(128, 4), 256, 0, stream>>>(xbf, B2b, nullptr, fT, cb2, 2048, 0);
  ln_fT<<<NST, 256, 0, stream>>>(fT, g1, lb1, g2, lb2);
  triu_pool<<<NST, 512, 0, stream>>>(xT, fT, W1bf, b1p, w2cp, b2s, pooled, pooledbf);

  // fused q|k|v: M=2048 N=1536 K=512
  gemm_bt<2><<<dim3(16, 12), 256, 0, stream>>>(pooledbf, Bqkv, qkvb, nullptr, bqkv, 512, 1536);

  attn_kernel<<<dim3(64, 8), 256, 0, stream>>>(qkvb, offs, perm, attnv);
  final_kernel<<<512, 256, 0, stream>>>(pooled, attnv, wp, wowp, cbuf, out);
}

// Round 7
// 559.673 us; speedup vs baseline: 3.1872x; 1.0843x over previous
//
#include <hip/hip_runtime.h>

#define NST 2048   // stocks

typedef __attribute__((ext_vector_type(8))) short bf16x8;
typedef __attribute__((ext_vector_type(4))) float f32x4;
typedef __attribute__((ext_vector_type(8))) unsigned short u16x8;

__device__ __forceinline__ float hswish(float x) {
  return x * fminf(fmaxf(x + 3.f, 0.f), 6.f) * (1.f / 6.f);
}

__device__ __forceinline__ unsigned short f2bf(float f) {
  unsigned int u = __float_as_uint(f);
  u += 0x7fffu + ((u >> 16) & 1u);
  return (unsigned short)(u >> 16);
}

__device__ __forceinline__ float bf2f(unsigned short b) {
  return __uint_as_float(((unsigned int)b) << 16);
}

__device__ __forceinline__ void gload16(const void* g, void* l) {
  __builtin_amdgcn_global_load_lds(
      (const __attribute__((address_space(1))) void*)g,
      (__attribute__((address_space(3))) void*)l, 16, 0, 0);
}

// ---------------------------------------------------------------------------
// x [2048,32,512] fp32 -> xbf [n][t][c] bf16  AND  xT [n][c][32] bf16.
// xT store: 4 lanes cover one 64B row -> wave stores 1KB contiguous.
// LDS pad 524: 8*262 = 2096 = 16 mod 32 -> 2-way bank aliasing (free).
// ---------------------------------------------------------------------------
__global__ __launch_bounds__(256) void x_prep(const float* __restrict__ x,
                                              unsigned short* __restrict__ xbf,
                                              unsigned short* __restrict__ xT) {
  __shared__ unsigned short T[32 * 524];
  const int n = blockIdx.x;
  const int tid = threadIdx.x;
  const float* xn = x + (long)n * 16384;
  unsigned short* xbn = xbf + (long)n * 16384;

#pragma unroll
  for (int i = 0; i < 16; i++) {
    int id = tid + i * 256;
    int flat = id * 4;
    float4 v = *(const float4*)(xn + flat);
    short4 o;
    o.x = (short)f2bf(v.x); o.y = (short)f2bf(v.y);
    o.z = (short)f2bf(v.z); o.w = (short)f2bf(v.w);
    *(short4*)(xbn + flat) = o;
    int t = flat >> 9, c = flat & 511;
    *(short4*)&T[t * 524 + c] = o;
  }
  __syncthreads();

  const int q = tid & 3;
  const int csub = tid >> 2;
#pragma unroll
  for (int rr = 0; rr < 8; rr++) {
    int c = rr * 64 + csub;
    u16x8 o;
#pragma unroll
    for (int j = 0; j < 8; j++) o[j] = T[(q * 8 + j) * 524 + c];
    *(u16x8*)(xT + (long)n * 16384 + c * 32 + q * 8) = o;
  }
}

// ---------------------------------------------------------------------------
// All weight prep in ONE kernel (block ranges):
//  [0,2048)    conv1 w -> B1b[co][k*512+ci]
//  [2048,6144) conv2 w -> B2b
//  [6144,9216) qkv w -> Bqkv[o][in] + bias concat
//  9216        triu prep (W1bf, w2cp, b1p, b2s)
//  [9217,9225) wowp rows + const
// ---------------------------------------------------------------------------
__global__ __launch_bounds__(256) void weights_prep(
    const float* __restrict__ w1, const float* __restrict__ w2,
    const float* __restrict__ wq, const float* __restrict__ wk,
    const float* __restrict__ wv, const float* __restrict__ bq,
    const float* __restrict__ bk, const float* __restrict__ bv,
    const float* __restrict__ tw1, const float* __restrict__ tb1,
    const float* __restrict__ tw2, const float* __restrict__ tb2,
    const float* __restrict__ wo, const float* __restrict__ wp,
    const float* __restrict__ bo, const float* __restrict__ bp,
    unsigned short* __restrict__ B1b, unsigned short* __restrict__ B2b,
    unsigned short* __restrict__ Bqkv, float* __restrict__ bqkv,
    unsigned short* __restrict__ W1bf, float* __restrict__ w2cp,
    float* __restrict__ b1p, float* __restrict__ b2s,
    float* __restrict__ wowp, float* __restrict__ cbuf) {
  const int b = blockIdx.x, tid = threadIdx.x;
  if (b < 2048) {                       // conv1 weights
    int id = b * 256 + tid;
    int co = id >> 10, idx = id & 1023, ci = idx & 511, k = idx >> 9;
    B1b[id] = f2bf(w1[((co << 9) + ci) * 2 + k]);
  } else if (b < 6144) {                // conv2 weights
    int id = (b - 2048) * 256 + tid;
    int co = id >> 11, idx = id & 2047, ci = idx & 511, k = idx >> 9;
    B2b[id] = f2bf(w2[((co << 9) + ci) * 4 + k]);
  } else if (b < 9216) {                // qkv weights
    int id = (b - 6144) * 256 + tid;
    int o = id >> 9, i = id & 511, oc = o & 511;
    const float* w = (o < 512) ? wq : (o < 1024) ? wk : wv;
    Bqkv[id] = f2bf(w[(i << 9) + oc]);
    if (i == 0) bqkv[o] = (o < 512) ? bq[oc] : (o < 1024) ? bk[oc] : bv[oc];
  } else if (b == 9216) {               // triu prep
#pragma unroll
    for (int i = 0; i < 16; i++) {
      int id = tid + i * 256;
      int s = id >> 6, t = id & 63;
      float v = (s < 56 && t < 56 && t <= s) ? tw1[s * 56 + t] : 0.f;
      W1bf[id] = f2bf(v);
    }
    if (tid < 64) {
      float sum = 0.f;
      if (tid < 56)
        for (int r = tid; r < 56; r++) sum += tw2[r * 56 + tid];
      w2cp[tid] = sum;
      b1p[tid] = (tid < 56) ? tb1[tid] : 0.f;
    }
    if (tid == 0) {
      float bb = 0.f;
      for (int s = 0; s < 56; s++) bb += tb2[s];
      b2s[0] = bb;
    }
  } else {                              // wowp (8 blocks)
    int w = tid >> 6, lane = tid & 63;
    int gw = (b - 9217) * 4 + w;
    for (int row = gw; row < 512; row += 32) {
      float partial = 0.f;
      for (int e = lane; e < 512; e += 64) partial += wo[(long)row * 512 + e] * wp[e];
      for (int d = 32; d; d >>= 1) partial += __shfl_xor(partial, d);
      if (lane == 0) wowp[row] = partial;
    }
    if (b == 9217 && w == 0) {
      float partial = 0.f;
      for (int e = lane; e < 512; e += 64) partial += bo[e] * wp[e];
      for (int d = 32; d; d >>= 1) partial += __shfl_xor(partial, d);
      if (lane == 0) cbuf[0] = partial + bp[0];
    }
  }
}

// ---------------------------------------------------------------------------
// Industry binning: one block, count/scan/scatter via LDS.
// ---------------------------------------------------------------------------
__global__ __launch_bounds__(1024) void binning(const int* __restrict__ ids,
                                                int* __restrict__ offs_g,
                                                int* __restrict__ perm) {
  __shared__ int cnt[64], cur[64], offs_s[65];
  const int tid = threadIdx.x;
  if (tid < 64) { cnt[tid] = 0; cur[tid] = 0; }
  __syncthreads();
  for (int n = tid; n < NST; n += 1024) atomicAdd(&cnt[ids[n]], 1);
  __syncthreads();
  if (tid < 64) {                       // tid<64 == wave 0
    int incl = cnt[tid];
    for (int d = 1; d < 64; d <<= 1) {
      int u = __shfl_up(incl, d);
      if (tid >= d) incl += u;
    }
    offs_s[tid + 1] = incl;
    offs_g[tid + 1] = incl;
    if (tid == 0) { offs_s[0] = 0; offs_g[0] = 0; }
  }
  __syncthreads();
  for (int n = tid; n < NST; n += 1024) {
    int g = ids[n];
    perm[offs_s[g] + atomicAdd(&cur[g], 1)] = n;
  }
}

// ---------------------------------------------------------------------------
// Fused conv1+conv2 bf16 MFMA GEMM -> fT[n][c][32] bf16.
// grid (384, 4): bx<256 = conv1 (M=32768,K=1024), else conv2 (M=16384,K=2048).
// ---------------------------------------------------------------------------
__global__ __launch_bounds__(256) void gemm_conv(
    const unsigned short* __restrict__ A, const unsigned short* __restrict__ B1,
    const unsigned short* __restrict__ B2, unsigned short* __restrict__ fT,
    const float* __restrict__ cb1, const float* __restrict__ cb2) {
  __shared__ unsigned short As[128 * 64];
  __shared__ unsigned short Bs[128 * 64];
  const int tid = threadIdx.x;
  const int wid = tid >> 6;
  const int lane = tid & 63;
  const bool isc1 = blockIdx.x < 256;
  const int bx = isc1 ? blockIdx.x : blockIdx.x - 256;
  const unsigned short* Bt = isc1 ? B1 : B2;
  const float* bias = isc1 ? cb1 : cb2;
  const int K = isc1 ? 1024 : 2048;
  const int r0 = bx * 128;
  const int c0 = blockIdx.y * 128;
  const int wr = (wid >> 1) * 64;
  const int wc = (wid & 1) * 64;
  const int srow = lane >> 3;
  const int sslot = lane & 7;

  long aoffl[4], boffl[4];
  unsigned short* adst[4];
  unsigned short* bdst[4];
#pragma unroll
  for (int l = 0; l < 4; l++) {
    const int r = (wid * 4 + l) * 8 + srow;
    const int gr = r0 + r;
    long ao;
    if (isc1) ao = (long)(((gr >> 4) * 32) + ((gr & 15) << 1)) << 9;
    else      ao = (long)(((gr >> 3) * 32) + ((gr & 7) << 2)) << 9;
    const int sw = (sslot ^ (r & 7)) << 3;
    aoffl[l] = ao + sw;
    boffl[l] = (long)(c0 + r) * K + sw;
    adst[l] = &As[(wid * 4 + l) * 8 * 64];
    bdst[l] = &Bs[(wid * 4 + l) * 8 * 64];
  }

  f32x4 acc[4][4];
#pragma unroll
  for (int m = 0; m < 4; m++)
#pragma unroll
    for (int n = 0; n < 4; n++) acc[m][n] = (f32x4){0.f, 0.f, 0.f, 0.f};

  const int fr = lane & 15;
  const int fq = lane >> 4;

  for (int kt = 0; kt < K; kt += 64) {
#pragma unroll
    for (int l = 0; l < 4; l++) {
      gload16(A + aoffl[l] + kt, adst[l]);
      gload16(Bt + boffl[l] + kt, bdst[l]);
    }
    __syncthreads();
#pragma unroll
    for (int ks = 0; ks < 2; ks++) {
      const int kq = ks * 4 + fq;
      bf16x8 af[4], bfr[4];
#pragma unroll
      for (int m = 0; m < 4; m++) {
        const int rr = wr + m * 16 + fr;
        af[m] = *(const bf16x8*)&As[rr * 64 + ((kq ^ (rr & 7)) << 3)];
      }
#pragma unroll
      for (int n = 0; n < 4; n++) {
        const int cc = wc + n * 16 + fr;
        bfr[n] = *(const bf16x8*)&Bs[cc * 64 + ((kq ^ (cc & 7)) << 3)];
      }
#pragma unroll
      for (int m = 0; m < 4; m++)
#pragma unroll
        for (int n = 0; n < 4; n++)
          acc[m][n] = __builtin_amdgcn_mfma_f32_16x16x32_bf16(
              af[m], bfr[n], acc[m][n], 0, 0, 0);
    }
    __syncthreads();
  }

  float bv[4];
#pragma unroll
  for (int n = 0; n < 4; n++) bv[n] = bias[c0 + wc + n * 16 + fr];

#pragma unroll
  for (int m = 0; m < 4; m++) {
    const int gr = r0 + wr + m * 16 + fq * 4;
    int nst, e0;
    if (isc1) { nst = gr >> 4; e0 = gr & 15; }
    else      { nst = gr >> 3; e0 = 16 + (gr & 7); }
#pragma unroll
    for (int n = 0; n < 4; n++) {
      const int cc = c0 + wc + n * 16 + fr;
      short4 o;
      o.x = (short)f2bf(acc[m][n][0] + bv[n]);
      o.y = (short)f2bf(acc[m][n][1] + bv[n]);
      o.z = (short)f2bf(acc[m][n][2] + bv[n]);
      o.w = (short)f2bf(acc[m][n][3] + bv[n]);
      *(short4*)(fT + ((long)(nst * 512 + cc) * 32 + e0)) = o;
    }
  }
}

// ---------------------------------------------------------------------------
// Plain bf16 MFMA GEMM for qkv: C[M,ldc] fp32.
// ---------------------------------------------------------------------------
__global__ __launch_bounds__(256) void gemm_qkv(
    const unsigned short* __restrict__ A, const unsigned short* __restrict__ Bt,
    float* __restrict__ C, const float* __restrict__ bias, int K, int ldc) {
  __shared__ unsigned short As[128 * 64];
  __shared__ unsigned short Bs[128 * 64];
  const int tid = threadIdx.x;
  const int wid = tid >> 6;
  const int lane = tid & 63;
  const int r0 = blockIdx.x * 128;
  const int c0 = blockIdx.y * 128;
  const int wr = (wid >> 1) * 64;
  const int wc = (wid & 1) * 64;
  const int srow = lane >> 3;
  const int sslot = lane & 7;

  long aoffl[4], boffl[4];
  unsigned short* adst[4];
  unsigned short* bdst[4];
#pragma unroll
  for (int l = 0; l < 4; l++) {
    const int r = (wid * 4 + l) * 8 + srow;
    const int gr = r0 + r;
    const int sw = (sslot ^ (r & 7)) << 3;
    aoffl[l] = (long)gr * K + sw;
    boffl[l] = (long)(c0 + r) * K + sw;
    adst[l] = &As[(wid * 4 + l) * 8 * 64];
    bdst[l] = &Bs[(wid * 4 + l) * 8 * 64];
  }

  f32x4 acc[4][4];
#pragma unroll
  for (int m = 0; m < 4; m++)
#pragma unroll
    for (int n = 0; n < 4; n++) acc[m][n] = (f32x4){0.f, 0.f, 0.f, 0.f};

  const int fr = lane & 15;
  const int fq = lane >> 4;

  for (int kt = 0; kt < K; kt += 64) {
#pragma unroll
    for (int l = 0; l < 4; l++) {
      gload16(A + aoffl[l] + kt, adst[l]);
      gload16(Bt + boffl[l] + kt, bdst[l]);
    }
    __syncthreads();
#pragma unroll
    for (int ks = 0; ks < 2; ks++) {
      const int kq = ks * 4 + fq;
      bf16x8 af[4], bfr[4];
#pragma unroll
      for (int m = 0; m < 4; m++) {
        const int rr = wr + m * 16 + fr;
        af[m] = *(const bf16x8*)&As[rr * 64 + ((kq ^ (rr & 7)) << 3)];
      }
#pragma unroll
      for (int n = 0; n < 4; n++) {
        const int cc = wc + n * 16 + fr;
        bfr[n] = *(const bf16x8*)&Bs[cc * 64 + ((kq ^ (cc & 7)) << 3)];
      }
#pragma unroll
      for (int m = 0; m < 4; m++)
#pragma unroll
        for (int n = 0; n < 4; n++)
          acc[m][n] = __builtin_amdgcn_mfma_f32_16x16x32_bf16(
              af[m], bfr[n], acc[m][n], 0, 0, 0);
    }
    __syncthreads();
  }

  float bv[4];
#pragma unroll
  for (int n = 0; n < 4; n++) bv[n] = bias[c0 + wc + n * 16 + fr];

#pragma unroll
  for (int m = 0; m < 4; m++)
#pragma unroll
    for (int j = 0; j < 4; j++) {
      const int gr = r0 + wr + m * 16 + fq * 4 + j;
      float* cp = C + (long)gr * ldc + c0 + wc + fr;
#pragma unroll
      for (int n = 0; n < 4; n++) cp[n * 16] = acc[m][n][j] + bv[n];
    }
}

// ---------------------------------------------------------------------------
// TriU stage1 MFMA + FUSED LayerNorm (stats+apply in LDS) + folded
// stage2*pool epilogue.  One block per stock, 8 waves.
// Zt slots (logical): 0-3 = xT t0..31, 4-5 = f1 ts0..15, 6 = f2 ts0..7,
// 7 = pad (zeroed in LDS).  Physical slot = logical ^ (c&7).
// ---------------------------------------------------------------------------
__global__ __launch_bounds__(512, 4) void triu_pool(
    const unsigned short* __restrict__ xT, const unsigned short* __restrict__ fT,
    const unsigned short* __restrict__ W1bf, const float* __restrict__ b1p,
    const float* __restrict__ w2cp, const float* __restrict__ b2s,
    const float* __restrict__ g1, const float* __restrict__ lb1,
    const float* __restrict__ g2, const float* __restrict__ lb2,
    float* __restrict__ pooled, unsigned short* __restrict__ pooledbf) {
  __shared__ unsigned short Zt[512 * 64];
  __shared__ float red[8][4];
  const int tid = threadIdx.x;
  const int wid = tid >> 6;
  const int lane = tid & 63;
  const int n = blockIdx.x;
  const int fr = lane & 15;
  const int fq = lane >> 4;

  const unsigned short* xTn = xT + (long)n * 16384;
  const unsigned short* fTn = fT + (long)n * 16384;

  // ---- stage (raw, pre-LN) ----
#pragma unroll
  for (int cb = 0; cb < 8; cb++) {
    const int cbase = wid * 64 + cb * 8;
    const int c = cbase + (lane >> 3);
    const int slot = lane & 7;
    const int slotp = slot ^ (c & 7);
    const unsigned short* src = (slotp < 4)
        ? (xTn + c * 32 + slotp * 8)
        : (fTn + c * 32 + (slotp - 4) * 8);
    gload16(src, &Zt[cbase * 64]);
  }
  __syncthreads();

  // ---- LN stats: thread c = tid owns channel row c ----
  const int c = tid;
  const int cx = c & 7;
  bf16x8 f1a = *(const bf16x8*)&Zt[c * 64 + ((4 ^ cx) << 3)];
  bf16x8 f1b = *(const bf16x8*)&Zt[c * 64 + ((5 ^ cx) << 3)];
  bf16x8 f2a = *(const bf16x8*)&Zt[c * 64 + ((6 ^ cx) << 3)];
  float s1 = 0.f, q1 = 0.f, s2 = 0.f, q2 = 0.f;
#pragma unroll
  for (int j = 0; j < 8; j++) {
    float a = bf2f((unsigned short)f1a[j]);
    float b = bf2f((unsigned short)f1b[j]);
    float d = bf2f((unsigned short)f2a[j]);
    s1 += a + b; q1 += a * a + b * b;
    s2 += d;     q2 += d * d;
  }
  for (int d = 32; d; d >>= 1) {
    s1 += __shfl_xor(s1, d); q1 += __shfl_xor(q1, d);
    s2 += __shfl_xor(s2, d); q2 += __shfl_xor(q2, d);
  }
  if (lane == 0) { red[wid][0] = s1; red[wid][1] = q1; red[wid][2] = s2; red[wid][3] = q2; }
  __syncthreads();
  float S1 = 0.f, Q1 = 0.f, S2 = 0.f, Q2 = 0.f;
#pragma unroll
  for (int wv = 0; wv < 8; wv++) {
    S1 += red[wv][0]; Q1 += red[wv][1]; S2 += red[wv][2]; Q2 += red[wv][3];
  }
  const float m1 = S1 / 8192.f;
  const float r1 = rsqrtf(Q1 / 8192.f - m1 * m1 + 1e-5f);
  const float m2 = S2 / 4096.f;
  const float r2 = rsqrtf(Q2 / 4096.f - m2 * m2 + 1e-5f);

  // ---- apply LN in LDS + zero pad slot ----
  u16x8 o1a, o1b, o2a, zz;
#pragma unroll
  for (int j = 0; j < 8; j++) {
    o1a[j] = f2bf((bf2f((unsigned short)f1a[j]) - m1) * r1 * g1[j * 512 + c] + lb1[j * 512 + c]);
    o1b[j] = f2bf((bf2f((unsigned short)f1b[j]) - m1) * r1 * g1[(8 + j) * 512 + c] + lb1[(8 + j) * 512 + c]);
    o2a[j] = f2bf((bf2f((unsigned short)f2a[j]) - m2) * r2 * g2[j * 512 + c] + lb2[j * 512 + c]);
    zz[j] = 0;
  }
  *(u16x8*)&Zt[c * 64 + ((4 ^ cx) << 3)] = o1a;
  *(u16x8*)&Zt[c * 64 + ((5 ^ cx) << 3)] = o1b;
  *(u16x8*)&Zt[c * 64 + ((6 ^ cx) << 3)] = o2a;
  *(u16x8*)&Zt[c * 64 + ((7 ^ cx) << 3)] = zz;
  __syncthreads();

  // ---- MFMA: A = tril(W1) bf16 [64s x 64t], B = Zt ----
  bf16x8 afr[4][2];
#pragma unroll
  for (int m = 0; m < 4; m++)
#pragma unroll
    for (int ks = 0; ks < 2; ks++)
      afr[m][ks] = *(const bf16x8*)(W1bf + (m * 16 + fr) * 64 + ks * 32 + fq * 8);

  f32x4 acc[4][4];
#pragma unroll
  for (int m = 0; m < 4; m++)
#pragma unroll
    for (int nn = 0; nn < 4; nn++) acc[m][nn] = (f32x4){0.f, 0.f, 0.f, 0.f};

#pragma unroll
  for (int nn = 0; nn < 4; nn++) {
    const int cc = wid * 64 + nn * 16 + fr;
#pragma unroll
    for (int ks = 0; ks < 2; ks++) {
      const int slot = (ks * 4 + fq) ^ (cc & 7);
      bf16x8 bfrag = *(const bf16x8*)&Zt[cc * 64 + slot * 8];
#pragma unroll
      for (int m = 0; m < 4; m++)
        acc[m][nn] = __builtin_amdgcn_mfma_f32_16x16x32_bf16(
            afr[m][ks], bfrag, acc[m][nn], 0, 0, 0);
    }
  }

  float b1r[16], w2r[16];
#pragma unroll
  for (int m = 0; m < 4; m++)
#pragma unroll
    for (int j = 0; j < 4; j++) {
      int s = m * 16 + fq * 4 + j;
      b1r[m * 4 + j] = b1p[s];
      w2r[m * 4 + j] = w2cp[s];
    }
  const float b2sum = b2s[0];

#pragma unroll
  for (int nn = 0; nn < 4; nn++) {
    float cs = 0.f;
#pragma unroll
    for (int m = 0; m < 4; m++)
#pragma unroll
      for (int j = 0; j < 4; j++)
        cs = fmaf(hswish(acc[m][nn][j] + b1r[m * 4 + j]), w2r[m * 4 + j], cs);
    cs += __shfl_xor(cs, 16);
    cs += __shfl_xor(cs, 32);
    if (fq == 0) {
      const int cc = wid * 64 + nn * 16 + fr;
      float pv = (cs + b2sum) * (1.f / 56.f);
      pooled[(long)n * 512 + cc] = pv;
      pooledbf[(long)n * 512 + cc] = f2bf(pv);
    }
  }
}

// ---------------------------------------------------------------------------
// Block-sparse attention, LDS-staged & lane-parallel (unchanged from R6).
// ---------------------------------------------------------------------------
__global__ __launch_bounds__(256) void attn_kernel(
    const float* __restrict__ qkv, const int* __restrict__ offs,
    const int* __restrict__ perm, float* __restrict__ attnv) {
  const int g = blockIdx.x, h = blockIdx.y;
  const int off = offs[g];
  const int S = offs[g + 1] - off;
  const int tid = threadIdx.x;
  const int w = tid >> 6, lane = tid & 63;

  __shared__ float Ks[128 * 66];
  __shared__ float Vs[128 * 64];
  __shared__ float Ps[4][128];
  __shared__ float Qw[4][64];

  if (S <= 128) {
    for (int idx = tid; idx < S * 16; idx += 256) {
      const int row = idx >> 4, q4 = (idx & 15) * 4;
      const int mj = perm[off + row];
      const float* base = qkv + (long)mj * 1536 + h * 64 + q4;
      float4 kv = *(const float4*)(base + 512);
      float4 vv = *(const float4*)(base + 1024);
      float* kr = &Ks[row * 66 + q4];
      kr[0] = kv.x; kr[1] = kv.y; kr[2] = kv.z; kr[3] = kv.w;
      *(float4*)&Vs[row * 64 + q4] = vv;
    }
    __syncthreads();

    for (int i = w; i < S; i += 4) {
      const int mi = perm[off + i];
      const float qd = qkv[(long)mi * 1536 + h * 64 + lane];
      Qw[w][lane] = qd;

      float sc0 = -1e30f, sc1 = -1e30f;
      {
        const int j = lane;
        if (j < S) {
          float a = 0.f;
          const float* kr = &Ks[j * 66];
#pragma unroll
          for (int t = 0; t < 32; t++) {
            float2 k2 = *(const float2*)(kr + 2 * t);
            float2 q2 = *(const float2*)&Qw[w][2 * t];
            a = fmaf(q2.x, k2.x, a);
            a = fmaf(q2.y, k2.y, a);
          }
          sc0 = a * 0.125f;
        }
      }
      if (S > 64) {
        const int j = 64 + lane;
        if (j < S) {
          float a = 0.f;
          const float* kr = &Ks[j * 66];
#pragma unroll
          for (int t = 0; t < 32; t++) {
            float2 k2 = *(const float2*)(kr + 2 * t);
            float2 q2 = *(const float2*)&Qw[w][2 * t];
            a = fmaf(q2.x, k2.x, a);
            a = fmaf(q2.y, k2.y, a);
          }
          sc1 = a * 0.125f;
        }
      }
      float m = fmaxf(sc0, sc1);
      for (int d = 32; d; d >>= 1) m = fmaxf(m, __shfl_xor(m, d));
      float p0 = (lane < S) ? __expf(sc0 - m) : 0.f;
      float p1 = (64 + lane < S) ? __expf(sc1 - m) : 0.f;
      float l = p0 + p1;
      for (int d = 32; d; d >>= 1) l += __shfl_xor(l, d);
      Ps[w][lane] = p0;
      Ps[w][64 + lane] = p1;

      float o = 0.f;
      for (int j = 0; j < S; j++)
        o = fmaf(Ps[w][j], Vs[j * 64 + lane], o);
      attnv[(long)mi * 512 + h * 64 + lane] = o / l;
    }
  } else {
    __shared__ float pbuf[4][64];
    __shared__ int jbuf[4][64];
    for (int i = w; i < S; i += 4) {
      const int mi = perm[off + i];
      const float* qp = qkv + (long)mi * 1536 + h * 64;
      float m_run = -1e30f, l_run = 0.f, o_d = 0.f;
      for (int jb = 0; jb < S; jb += 64) {
        int jc = min(64, S - jb);
        int mj = (lane < jc) ? perm[off + jb + lane] : 0;
        float sc = -1e30f;
        if (lane < jc) {
          const float* kp = qkv + (long)mj * 1536 + 512 + h * 64;
          float a = 0.f;
#pragma unroll
          for (int d4 = 0; d4 < 16; d4++) {
            float4 qv = *(const float4*)(qp + d4 * 4);
            float4 kv = *(const float4*)(kp + d4 * 4);
            a += qv.x * kv.x + qv.y * kv.y + qv.z * kv.z + qv.w * kv.w;
          }
          sc = a * 0.125f;
        }
        float cm = sc;
        for (int d = 32; d; d >>= 1) cm = fmaxf(cm, __shfl_xor(cm, d));
        float m_new = fmaxf(m_run, cm);
        float resc = __expf(m_run - m_new);
        float p = (lane < jc) ? __expf(sc - m_new) : 0.f;
        float cs = p;
        for (int d = 32; d; d >>= 1) cs += __shfl_xor(cs, d);
        l_run = l_run * resc + cs;
        pbuf[w][lane] = p;
        jbuf[w][lane] = mj;
        float onew = o_d * resc;
        for (int j = 0; j < jc; j++)
          onew = fmaf(pbuf[w][j], qkv[(long)jbuf[w][j] * 1536 + 1024 + h * 64 + lane], onew);
        o_d = onew;
        m_run = m_new;
      }
      attnv[(long)mi * 512 + h * 64 + lane] = o_d / l_run;
    }
  }
}

__global__ void final_kernel(const float* __restrict__ pooled,
                             const float* __restrict__ attnv,
                             const float* __restrict__ wp,
                             const float* __restrict__ wowp,
                             const float* __restrict__ constbuf,
                             float* __restrict__ out) {
  int w = threadIdx.x >> 6, lane = threadIdx.x & 63;
  int row = blockIdx.x * 4 + w;
  float partial = 0.f;
#pragma unroll
  for (int e8 = 0; e8 < 8; e8++) {
    int e = lane + e8 * 64;
    partial += pooled[(long)row * 512 + e] * wp[e] + attnv[(long)row * 512 + e] * wowp[e];
  }
  for (int d = 32; d; d >>= 1) partial += __shfl_xor(partial, d);
  if (lane == 0) out[row] = partial + constbuf[0];
}

// ---------------------------------------------------------------------------
extern "C" void kernel_launch(void* const* d_in, const int* in_sizes, int n_in,
                              void* d_out, int out_size, void* d_ws, size_t ws_size,
                              hipStream_t stream) {
  const float* x   = (const float*)d_in[0];
  const int*   ids = (const int*)d_in[1];
  const float* w1  = (const float*)d_in[2];
  const float* cb1 = (const float*)d_in[3];
  const float* w2  = (const float*)d_in[4];
  const float* cb2 = (const float*)d_in[5];
  const float* g1  = (const float*)d_in[6];
  const float* lb1 = (const float*)d_in[7];
  const float* g2  = (const float*)d_in[8];
  const float* lb2 = (const float*)d_in[9];
  const float* tw1 = (const float*)d_in[10];
  const float* tb1 = (const float*)d_in[11];
  const float* tw2 = (const float*)d_in[12];
  const float* tb2 = (const float*)d_in[13];
  const float* wq  = (const float*)d_in[14];
  const float* bq  = (const float*)d_in[15];
  const float* wk  = (const float*)d_in[16];
  const float* bk  = (const float*)d_in[17];
  const float* wv  = (const float*)d_in[18];
  const float* bv  = (const float*)d_in[19];
  const float* wo  = (const float*)d_in[20];
  const float* bo  = (const float*)d_in[21];
  const float* wp  = (const float*)d_in[22];
  const float* bp  = (const float*)d_in[23];
  float* out = (float*)d_out;

  char* ws = (char*)d_ws;
  size_t off = 0;
  auto alloc = [&](size_t bytes) {
    void* p = ws + off;
    off += (bytes + 255) & ~(size_t)255;
    return p;
  };
  unsigned short* xbf  = (unsigned short*)alloc((size_t)NST * 32 * 512 * 2);
  unsigned short* xT   = (unsigned short*)alloc((size_t)NST * 512 * 32 * 2);
  unsigned short* fT   = (unsigned short*)alloc((size_t)NST * 512 * 32 * 2);
  unsigned short* B1b  = (unsigned short*)alloc((size_t)512 * 1024 * 2);
  unsigned short* B2b  = (unsigned short*)alloc((size_t)512 * 2048 * 2);
  unsigned short* Bqkv = (unsigned short*)alloc((size_t)1536 * 512 * 2);
  float* bqkv   = (float*)alloc(1536 * 4);
  unsigned short* W1bf = (unsigned short*)alloc(64 * 64 * 2);
  float* w2cp   = (float*)alloc(64 * 4);
  float* b1p    = (float*)alloc(64 * 4);
  float* b2s    = (float*)alloc(4);
  float* pooled = (float*)alloc((size_t)NST * 512 * 4);
  unsigned short* pooledbf = (unsigned short*)alloc((size_t)NST * 512 * 2);
  float* qkvb   = (float*)alloc((size_t)NST * 1536 * 4);
  float* attnv  = (float*)alloc((size_t)NST * 512 * 4);
  float* wowp   = (float*)alloc(512 * 4);
  float* cbuf   = (float*)alloc(4);
  int* offs     = (int*)alloc(65 * 4);
  int* perm     = (int*)alloc(NST * 4);

  // prep (3 launches)
  weights_prep<<<9225, 256, 0, stream>>>(w1, w2, wq, wk, wv, bq, bk, bv,
                                         tw1, tb1, tw2, tb2, wo, wp, bo, bp,
                                         B1b, B2b, Bqkv, bqkv, W1bf, w2cp, b1p, b2s,
                                         wowp, cbuf);
  binning<<<1, 1024, 0, stream>>>(ids, offs, perm);
  x_prep<<<NST, 256, 0, stream>>>(x, xbf, xT);

  // conv1+conv2 fused GEMM -> fT bf16
  gemm_conv<<<dim3(384, 4), 256, 0, stream>>>(xbf, B1b, B2b, fT, cb1, cb2);

  // TriU + fused LN + pool
  triu_pool<<<NST, 512, 0, stream>>>(xT, fT, W1bf, b1p, w2cp, b2s,
                                     g1, lb1, g2, lb2, pooled, pooledbf);

  // fused q|k|v: M=2048 N=1536 K=512
  gemm_qkv<<<dim3(16, 12), 256, 0, stream>>>(pooledbf, Bqkv, qkvb, bqkv, 512, 1536);

  attn_kernel<<<dim3(64, 8), 256, 0, stream>>>(qkvb, offs, perm, attnv);
  final_kernel<<<512, 256, 0, stream>>>(pooled, attnv, wp, wowp, cbuf, out);
}